// Round 1
// baseline (3712.205 us; speedup 1.0000x reference)
//
#include <hip/hip_runtime.h>
#include <math.h>

// Problem constants
#define NB 2048            // batch
#define ZD 2048            // z dim = 2*512 + 1024, also D_H
#define SD 512             // state dim
#define NELEM_Z (NB * ZD)  // 4194304

__device__ __forceinline__ float softplus_f(float x) {
  if (x > 20.f) return x;
  if (x < -20.f) return expf(x);
  return log1pf(expf(x));
}

// ---------------------------------------------------------------------------
// Build z = [q, p, x] (B x 2048) and zero the reduction accumulator.
// h_padded flat: b*2048 + s*128 + m ; unpacked i=s*128+m for s<8 -> same flat.
// ---------------------------------------------------------------------------
__global__ void build_z_kernel(const float* __restrict__ x,
                               const float* __restrict__ h_padded,
                               float* __restrict__ z,
                               float* __restrict__ acc) {
  int idx = blockIdx.x * blockDim.x + threadIdx.x;
  if (idx == 0) acc[0] = 0.f;
  int b = idx >> 11;
  int i = idx & 2047;
  float v;
  if (i < 1024) v = h_padded[idx];              // q (0:512) then p (512:1024)
  else          v = x[b * 1024 + (i - 1024)];   // x
  z[idx] = v;
}

// ---------------------------------------------------------------------------
// VQC: one 64-thread block per batch row. State amplitude lives one-per-lane.
// ctrl = [x, q, p]:  ctrl[j] = (j<1024) ? z[b][1024+j] : z[b][j-1024]
// ---------------------------------------------------------------------------
__global__ void vqc_kernel(const float* __restrict__ z,
                           const float* __restrict__ enc_W,  // (2048,6)
                           const float* __restrict__ enc_b,  // (6,)
                           const float* __restrict__ thetas, // (3,6)
                           const float* __restrict__ gain,
                           const float* __restrict__ shift,
                           float* __restrict__ acc) {
  int b = blockIdx.x;
  int lane = threadIdx.x;  // 0..63
  const float* zb = z + b * ZD;

  // angles = ctrl @ enc_W + enc_b
  float pa[6] = {0.f, 0.f, 0.f, 0.f, 0.f, 0.f};
  for (int j = lane; j < 2048; j += 64) {
    float c = (j < 1024) ? zb[1024 + j] : zb[j - 1024];
    const float* w = enc_W + j * 6;
#pragma unroll
    for (int k = 0; k < 6; k++) pa[k] += c * w[k];
  }
#pragma unroll
  for (int k = 0; k < 6; k++) {
    for (int off = 32; off > 0; off >>= 1) pa[k] += __shfl_down(pa[k], off, 64);
    pa[k] = __shfl(pa[k], 0, 64) + enc_b[k];
  }

  // statevector sim: qubit k lives at bit (5-k) of the lane index
  float s = (lane == 0) ? 1.f : 0.f;
  int rot = ((lane << 1) | (lane >> 5)) & 63;
  float cz = (__popc(lane & rot) & 1) ? -1.f : 1.f;

#pragma unroll
  for (int k = 0; k < 6; k++) {
    float half = 0.5f * pa[k];
    float c = cosf(half), si = sinf(half);
    int m = 1 << (5 - k);
    float other = __shfl_xor(s, m, 64);
    s = (lane & m) ? (si * other + c * s) : (c * s - si * other);
  }
  for (int l = 0; l < 3; l++) {
#pragma unroll
    for (int k = 0; k < 6; k++) {
      float half = 0.5f * thetas[l * 6 + k];
      float c = cosf(half), si = sinf(half);
      int m = 1 << (5 - k);
      float other = __shfl_xor(s, m, 64);
      s = (lane & m) ? (si * other + c * s) : (c * s - si * other);
    }
    s *= cz;
  }

  float zobs = (6.f - 2.f * (float)__popc(lane)) * (1.f / 6.f);
  float val = s * s * zobs;
  for (int off = 32; off > 0; off >>= 1) val += __shfl_down(val, off, 64);

  if (lane == 0) {
    float sg = softplus_f(gain[0]);
    float ss = softplus_f(shift[0]);
    float adjusted = softplus_f(sg * val - ss);
    atomicAdd(acc, adjusted);
  }
}

// ---------------------------------------------------------------------------
// dt scalar chain
// ---------------------------------------------------------------------------
__global__ void dt_kernel(const float* __restrict__ acc,
                          const float* __restrict__ cap_param,
                          const float* __restrict__ time_bias,
                          const float* __restrict__ last_stable,
                          float* __restrict__ dt_out) {
  float raw = acc[0] * (1.f / (float)NB) + time_bias[0];
  float cap = fmaxf(softplus_f(cap_param[0]), 1e-6f);
  float evo = cap / (1.f + expf(-raw / cap));
  if (!isfinite(evo)) evo = cap / (1.f + expf(-time_bias[0] / cap));
  float prev = fmaxf(last_stable[0], 1e-6f);
  float cand = fmaxf(evo, 1e-6f);
  float max_step = fmaxf(prev * 0.1f, 1e-4f);
  cand = fminf(cand, prev + max_step);
  cand = fminf(cand, 0.05f);
  dt_out[0] = isfinite(cand) ? cand : prev;
}

// ---------------------------------------------------------------------------
// Tiled f32 GEMM: C[M,N] = epilogue( A[M,K] @ B )   (B normal K x N, or B^T
// where Bm is N x K row-major). BM=BN=64, BK=16, 256 thr, 4x4 micro-tile.
// EPI: 0 none | 1 tanh(v+bias[col]) | 2 (1-t^2)*aux[col], t=tanh(v+bias[col])
//      3 v*(1-H^2), H=aux[row*ldc+col] (in-place safe) | 4 v+bias[col]
// ---------------------------------------------------------------------------
template <int EPI, bool TRANSB>
__global__ __launch_bounds__(256) void gemm_kernel(
    const float* __restrict__ A, int lda,
    const float* __restrict__ Bm, int ldb,
    float* __restrict__ C, int ldc,
    const float* __restrict__ bias,
    const float* __restrict__ aux,
    int K) {
  __shared__ float As[64][17];  // [m][k], padded: conflict-free transpose store
  __shared__ float Bs[16][65];  // [k][n], padded for TRANSB store

  int tid = threadIdx.x;
  int tx = tid & 15, ty = tid >> 4;
  int row0 = blockIdx.y * 64, col0 = blockIdx.x * 64;

  float accv[4][4] = {};

  for (int k0 = 0; k0 < K; k0 += 16) {
    {
      int k = tid & 15, m = tid >> 4;
#pragma unroll
      for (int r = 0; r < 4; r++)
        As[m + 16 * r][k] = A[(long)(row0 + m + 16 * r) * lda + k0 + k];
    }
    if (!TRANSB) {
      int n = tid & 63, kk = tid >> 6;
#pragma unroll
      for (int r = 0; r < 4; r++)
        Bs[kk + 4 * r][n] = Bm[(long)(k0 + kk + 4 * r) * ldb + col0 + n];
    } else {
      int kk = tid & 15, n = tid >> 4;
#pragma unroll
      for (int r = 0; r < 4; r++)
        Bs[kk][n + 16 * r] = Bm[(long)(col0 + n + 16 * r) * ldb + k0 + kk];
    }
    __syncthreads();

#pragma unroll
    for (int kk = 0; kk < 16; kk++) {
      float a[4], bb[4];
#pragma unroll
      for (int i = 0; i < 4; i++) a[i] = As[4 * ty + i][kk];
#pragma unroll
      for (int j = 0; j < 4; j++) bb[j] = Bs[kk][4 * tx + j];
#pragma unroll
      for (int i = 0; i < 4; i++)
#pragma unroll
        for (int j = 0; j < 4; j++) accv[i][j] = fmaf(a[i], bb[j], accv[i][j]);
    }
    __syncthreads();
  }

#pragma unroll
  for (int i = 0; i < 4; i++) {
    int row = row0 + 4 * ty + i;
#pragma unroll
    for (int j = 0; j < 4; j++) {
      int col = col0 + 4 * tx + j;
      long idx = (long)row * ldc + col;
      float v = accv[i][j];
      if (EPI == 0) {
        C[idx] = v;
      } else if (EPI == 1) {
        C[idx] = tanhf(v + bias[col]);
      } else if (EPI == 2) {
        float t = tanhf(v + bias[col]);
        C[idx] = (1.f - t * t) * aux[col];
      } else if (EPI == 3) {
        float h = aux[idx];
        C[idx] = v * (1.f - h * h);
      } else {
        C[idx] = v + bias[col];
      }
    }
  }
}

// ---------------------------------------------------------------------------
// z[:, off:off+512] += coef * dt * grad
// ---------------------------------------------------------------------------
__global__ void update_kernel(float* __restrict__ z,
                              const float* __restrict__ grad,
                              const float* __restrict__ dt,
                              float coef, int off) {
  int idx = blockIdx.x * blockDim.x + threadIdx.x;  // 2048*512
  int b = idx >> 9, j = idx & 511;
  z[b * ZD + off + j] += coef * dt[0] * grad[idx];
}

// ---------------------------------------------------------------------------
// h_next: first 8 slices = z[:, :1024], rest zero
// ---------------------------------------------------------------------------
__global__ void hnext_kernel(const float* __restrict__ z,
                             float* __restrict__ out) {
  int idx = blockIdx.x * blockDim.x + threadIdx.x;  // 2048*2048
  int b = idx >> 11, i = idx & 2047;
  out[idx] = (i < 1024) ? z[b * ZD + i] : 0.f;
}

// ---------------------------------------------------------------------------
extern "C" void kernel_launch(void* const* d_in, const int* in_sizes, int n_in,
                              void* d_out, int out_size, void* d_ws,
                              size_t ws_size, hipStream_t stream) {
  const float* x        = (const float*)d_in[0];
  const float* h_padded = (const float*)d_in[1];
  // d_in[2] aux_padded unused
  const float* W1    = (const float*)d_in[3];
  const float* b1    = (const float*)d_in[4];
  const float* W2    = (const float*)d_in[5];
  const float* b2    = (const float*)d_in[6];
  const float* W3    = (const float*)d_in[7];
  // d_in[8] b3 unused (constant offset, no gradient effect)
  const float* W_out = (const float*)d_in[9];
  const float* b_out = (const float*)d_in[10];
  const float* enc_W = (const float*)d_in[11];
  const float* enc_b = (const float*)d_in[12];
  const float* thetas = (const float*)d_in[13];
  const float* gain   = (const float*)d_in[14];
  const float* shift  = (const float*)d_in[15];
  const float* cap_p  = (const float*)d_in[16];
  const float* t_bias = (const float*)d_in[17];
  const float* l_stab = (const float*)d_in[18];

  float* out_mat  = (float*)d_out;                 // (2048,1024)
  float* out_hnxt = (float*)d_out + NB * 1024;     // (2048,16,128)

  // workspace layout (floats)
  float* ws   = (float*)d_ws;
  float* z    = ws;                 // 4M  : [q,p,x]
  float* h1   = z + NELEM_Z;        // 4M  : tanh(zW1+b1), later g1 in-place
  float* t1   = h1 + NELEM_Z;       // 4M  : g2 = (1-h2^2)*W3
  float* grad = t1 + NELEM_Z;       // 1M  : (B,512)
  float* accp = grad + NB * SD;     // 1
  float* dtp  = accp + 1;           // 1

  dim3 thr256(256);

  // 1. build z + zero acc
  build_z_kernel<<<dim3(NELEM_Z / 256), thr256, 0, stream>>>(x, h_padded, z, accp);

  // 2. VQC -> sum of adjusted into acc
  vqc_kernel<<<dim3(NB), dim3(64), 0, stream>>>(z, enc_W, enc_b, thetas, gain,
                                                shift, accp);

  // 3. dt scalar
  dt_kernel<<<dim3(1), dim3(1), 0, stream>>>(accp, cap_p, t_bias, l_stab, dtp);

  // 4. three leapfrog gradient evaluations
  // i=0: grad_q at (q,p)        -> p_half = p - 0.5*dt*g   (W1 rows 0,   off 512, -0.5)
  // i=1: grad_p at (q,p_half)   -> q_next = q + dt*g       (W1 rows 512, off 0,   +1.0)
  // i=2: grad_q at (q_next,p_h) -> p_next = p_h - 0.5*dt*g (W1 rows 0,   off 512, -0.5)
  const int   j0r[3]  = {0, 512, 0};
  const int   offs[3] = {512, 0, 512};
  const float coef[3] = {-0.5f, 1.0f, -0.5f};

  dim3 gridSq(ZD / 64, NB / 64);    // (32,32)
  dim3 gridGr(SD / 64, NB / 64);    // (8,32)

  for (int i = 0; i < 3; i++) {
    // h1 = tanh(z @ W1 + b1)
    gemm_kernel<1, false><<<gridSq, thr256, 0, stream>>>(
        z, ZD, W1, ZD, h1, ZD, b1, nullptr, ZD);
    // t1 = g2 = (1 - tanh(h1 @ W2 + b2)^2) * W3col
    gemm_kernel<2, false><<<gridSq, thr256, 0, stream>>>(
        h1, ZD, W2, ZD, t1, ZD, b2, W3, ZD);
    // h1 <- g1 = (g2 @ W2^T) * (1 - h1^2)   (in-place over h1)
    gemm_kernel<3, true><<<gridSq, thr256, 0, stream>>>(
        t1, ZD, W2, ZD, h1, ZD, nullptr, h1, ZD);
    // grad = g1 @ W1[j0r : j0r+512, :]^T
    gemm_kernel<0, true><<<gridGr, thr256, 0, stream>>>(
        h1, ZD, W1 + (long)j0r[i] * ZD, ZD, grad, SD, nullptr, nullptr, ZD);
    // z[:, offs] += coef * dt * grad
    update_kernel<<<dim3(NB * SD / 256), thr256, 0, stream>>>(
        z, grad, dtp, coef[i], offs[i]);
  }

  // 5. out = z[:, :1024] @ W_out + b_out
  gemm_kernel<4, false><<<dim3(1024 / 64, NB / 64), thr256, 0, stream>>>(
      z, ZD, W_out, 1024, out_mat, 1024, b_out, nullptr, 1024);

  // 6. h_next writeback
  hnext_kernel<<<dim3(NELEM_Z / 256), thr256, 0, stream>>>(z, out_hnxt);
}

// Round 2
// 800.341 us; speedup vs baseline: 4.6383x; 4.6383x over previous
//
#include <hip/hip_runtime.h>
#include <math.h>

// Problem constants
#define NB 2048            // batch
#define ZD 2048            // z dim = 2*512 + 1024, also D_H
#define SD 512             // state dim
#define NELEM_Z (NB * ZD)  // 4194304
#define MB_ (1024 * 1024)

typedef float f32x4 __attribute__((ext_vector_type(4)));
typedef __bf16 bf16x8 __attribute__((ext_vector_type(8)));
typedef __bf16 bf16x4 __attribute__((ext_vector_type(4)));

__device__ __forceinline__ float softplus_f(float x) {
  if (x > 20.f) return x;
  if (x < -20.f) return expf(x);
  return log1pf(expf(x));
}

__device__ __forceinline__ void gload_lds16(const __bf16* g, __bf16* l) {
  __builtin_amdgcn_global_load_lds(
      (__attribute__((address_space(1))) void*)(g),
      (__attribute__((address_space(3))) void*)(l), 16, 0, 0);
}

// ---------------------------------------------------------------------------
// Build z = [q, p, x] (B x 2048) f32 + bf16 mirror; zero the accumulator.
// ---------------------------------------------------------------------------
__global__ void build_z_kernel(const float* __restrict__ x,
                               const float* __restrict__ h_padded,
                               float* __restrict__ z,
                               __bf16* __restrict__ zb,
                               float* __restrict__ acc) {
  int idx = blockIdx.x * blockDim.x + threadIdx.x;
  if (idx == 0) acc[0] = 0.f;
  int b = idx >> 11;
  int i = idx & 2047;
  float v;
  if (i < 1024) v = h_padded[idx];              // q (0:512) then p (512:1024)
  else          v = x[b * 1024 + (i - 1024)];   // x
  z[idx] = v;
  zb[idx] = (__bf16)v;
}

// ---------------------------------------------------------------------------
// f32 -> bf16 flat convert (n multiple of 4*256)
// ---------------------------------------------------------------------------
__global__ void conv_f2b(const float* __restrict__ in, __bf16* __restrict__ out) {
  int i = blockIdx.x * blockDim.x + threadIdx.x;
  float4 v = ((const float4*)in)[i];
  bf16x4 o;
  o[0] = (__bf16)v.x; o[1] = (__bf16)v.y; o[2] = (__bf16)v.z; o[3] = (__bf16)v.w;
  ((bf16x4*)out)[i] = o;
}

// ---------------------------------------------------------------------------
// transpose + convert: in f32 (R x C) row-major -> out bf16 (C x R)
// block (32,8), grid (C/32, R/32)
// ---------------------------------------------------------------------------
__global__ void transpose_f2b(const float* __restrict__ in,
                              __bf16* __restrict__ out, int R, int C) {
  __shared__ float tile[32][33];
  int bx = blockIdx.x * 32, by = blockIdx.y * 32;
  int tx = threadIdx.x, ty = threadIdx.y;
  for (int r = ty; r < 32; r += 8)
    tile[r][tx] = in[(size_t)(by + r) * C + bx + tx];
  __syncthreads();
  for (int r = ty; r < 32; r += 8)
    out[(size_t)(bx + r) * R + by + tx] = (__bf16)tile[tx][r];
}

// ---------------------------------------------------------------------------
// VQC: one 64-thread block per batch row (dt saturates; precision-forgiving).
// ---------------------------------------------------------------------------
__global__ void vqc_kernel(const float* __restrict__ z,
                           const float* __restrict__ enc_W,  // (2048,6)
                           const float* __restrict__ enc_b,  // (6,)
                           const float* __restrict__ thetas, // (3,6)
                           const float* __restrict__ gain,
                           const float* __restrict__ shift,
                           float* __restrict__ acc) {
  int b = blockIdx.x;
  int lane = threadIdx.x;  // 0..63
  const float* zb = z + (size_t)b * ZD;

  float pa[6] = {0.f, 0.f, 0.f, 0.f, 0.f, 0.f};
  for (int j = lane; j < 2048; j += 64) {
    float c = (j < 1024) ? zb[1024 + j] : zb[j - 1024];
    const float* w = enc_W + j * 6;
#pragma unroll
    for (int k = 0; k < 6; k++) pa[k] += c * w[k];
  }
#pragma unroll
  for (int k = 0; k < 6; k++) {
    for (int off = 32; off > 0; off >>= 1) pa[k] += __shfl_down(pa[k], off, 64);
    pa[k] = __shfl(pa[k], 0, 64) + enc_b[k];
  }

  float s = (lane == 0) ? 1.f : 0.f;
  int rot = ((lane << 1) | (lane >> 5)) & 63;
  float cz = (__popc(lane & rot) & 1) ? -1.f : 1.f;

#pragma unroll
  for (int k = 0; k < 6; k++) {
    float half = 0.5f * pa[k];
    float c = cosf(half), si = sinf(half);
    int m = 1 << (5 - k);
    float other = __shfl_xor(s, m, 64);
    s = (lane & m) ? (si * other + c * s) : (c * s - si * other);
  }
  for (int l = 0; l < 3; l++) {
#pragma unroll
    for (int k = 0; k < 6; k++) {
      float half = 0.5f * thetas[l * 6 + k];
      float c = cosf(half), si = sinf(half);
      int m = 1 << (5 - k);
      float other = __shfl_xor(s, m, 64);
      s = (lane & m) ? (si * other + c * s) : (c * s - si * other);
    }
    s *= cz;
  }

  float zobs = (6.f - 2.f * (float)__popc(lane)) * (1.f / 6.f);
  float val = s * s * zobs;
  for (int off = 32; off > 0; off >>= 1) val += __shfl_down(val, off, 64);

  if (lane == 0) {
    float sg = softplus_f(gain[0]);
    float ss = softplus_f(shift[0]);
    atomicAdd(acc, softplus_f(sg * val - ss));
  }
}

// ---------------------------------------------------------------------------
// dt scalar chain
// ---------------------------------------------------------------------------
__global__ void dt_kernel(const float* __restrict__ acc,
                          const float* __restrict__ cap_param,
                          const float* __restrict__ time_bias,
                          const float* __restrict__ last_stable,
                          float* __restrict__ dt_out) {
  float raw = acc[0] * (1.f / (float)NB) + time_bias[0];
  float cap = fmaxf(softplus_f(cap_param[0]), 1e-6f);
  float evo = cap / (1.f + expf(-raw / cap));
  if (!isfinite(evo)) evo = cap / (1.f + expf(-time_bias[0] / cap));
  float prev = fmaxf(last_stable[0], 1e-6f);
  float cand = fmaxf(evo, 1e-6f);
  float max_step = fmaxf(prev * 0.1f, 1e-4f);
  cand = fminf(cand, prev + max_step);
  cand = fminf(cand, 0.05f);
  dt_out[0] = isfinite(cand) ? cand : prev;
}

// ---------------------------------------------------------------------------
// MFMA bf16 GEMM, m97 structure: C[M,N] = epi( A[M,K] @ Bt[N,K]^T )
// 128x128 tile, BK=32, 256 thr = 4 waves (2x2 of 64x64), 16x16x32 MFMA.
// LDS chunk layout with XOR swizzle: chunk (m-row, k-octet o) stored at chunk
// index m*4 + (o ^ ((m + (m>>2)) & 3))  -> 64B-coalesced global staging AND
// <=2-way-conflict ds_read_b128 fragment reads.
// EPI: 0 f32 split-K partial (C + z*M*ldc) | 1 bf16 tanh(v+bias[col])
//      2 bf16 (1-t^2)*auxf[col], t=tanh(v+bias[col])
//      3 bf16 v*(1-h^2), h=auxb[row*ldaux+col] | 4 f32 v+bias[col]
// ---------------------------------------------------------------------------
template <int EPI>
__global__ __launch_bounds__(256) void mfma_gemm(
    const __bf16* __restrict__ A, int lda,
    const __bf16* __restrict__ Bt, int ldb,
    void* __restrict__ Cv, int ldc,
    const float* __restrict__ bias,
    const void* __restrict__ aux, int ldaux,
    int Kslice) {
  __shared__ __bf16 sA[128 * 32];
  __shared__ __bf16 sB[128 * 32];

  const int tid = threadIdx.x;
  const int lane = tid & 63;
  const int w = tid >> 6;
  const int wm = w >> 1, wn = w & 1;
  const int row0 = blockIdx.y * 128;
  const int col0 = blockIdx.x * 128;
  const int koff = blockIdx.z * Kslice;

  // --- staging precompute: 2 chunks per thread per tile ---
  const int c0 = w * 128 + lane;
  const int c1 = c0 + 64;
  const int m0 = c0 >> 2, o0 = (c0 & 3) ^ ((m0 + (m0 >> 2)) & 3);
  const int m1 = c1 >> 2, o1 = (c1 & 3) ^ ((m1 + (m1 >> 2)) & 3);
  const __bf16* gA0 = A + (size_t)(row0 + m0) * lda + koff + o0 * 8;
  const __bf16* gA1 = A + (size_t)(row0 + m1) * lda + koff + o1 * 8;
  const __bf16* gB0 = Bt + (size_t)(col0 + m0) * ldb + koff + o0 * 8;
  const __bf16* gB1 = Bt + (size_t)(col0 + m1) * ldb + koff + o1 * 8;
  __bf16* lA0 = sA + c0 * 8;
  __bf16* lA1 = sA + c1 * 8;
  __bf16* lB0 = sB + c0 * 8;
  __bf16* lB1 = sB + c1 * 8;

  // --- fragment LDS offsets (k0-invariant) ---
  const int q = lane >> 4, r = lane & 15;
  int aoff[4], boff[4];
#pragma unroll
  for (int i = 0; i < 4; i++) {
    int ma = wm * 64 + i * 16 + r;
    aoff[i] = (ma * 4 + (q ^ ((ma + (ma >> 2)) & 3))) * 8;
    int mb = wn * 64 + i * 16 + r;
    boff[i] = (mb * 4 + (q ^ ((mb + (mb >> 2)) & 3))) * 8;
  }

  f32x4 acc[4][4] = {};

  for (int k0 = 0; k0 < Kslice; k0 += 32) {
    gload_lds16(gA0, lA0);
    gload_lds16(gA1, lA1);
    gload_lds16(gB0, lB0);
    gload_lds16(gB1, lB1);
    gA0 += 32; gA1 += 32; gB0 += 32; gB1 += 32;
    __syncthreads();  // drains vmcnt(0): staged data visible

    bf16x8 af[4], bfv[4];
#pragma unroll
    for (int i = 0; i < 4; i++) af[i] = *(const bf16x8*)(sA + aoff[i]);
#pragma unroll
    for (int j = 0; j < 4; j++) bfv[j] = *(const bf16x8*)(sB + boff[j]);
#pragma unroll
    for (int i = 0; i < 4; i++)
#pragma unroll
      for (int j = 0; j < 4; j++)
        acc[i][j] = __builtin_amdgcn_mfma_f32_16x16x32_bf16(af[i], bfv[j],
                                                            acc[i][j], 0, 0, 0);
    __syncthreads();  // LDS reads done before next stage
  }

  // --- epilogue: C/D layout col=lane&15, row=(lane>>4)*4+reg ---
  float* Cf = (float*)Cv;
  __bf16* Cb = (__bf16*)Cv;
  const float* auxf = (const float*)aux;
  const __bf16* auxb = (const __bf16*)aux;
  float* Cz = Cf + (size_t)blockIdx.z * (size_t)gridDim.y * 128 * ldc;

#pragma unroll
  for (int i = 0; i < 4; i++) {
    int rowb = row0 + wm * 64 + i * 16 + q * 4;
#pragma unroll
    for (int j = 0; j < 4; j++) {
      int col = col0 + wn * 64 + j * 16 + r;
#pragma unroll
      for (int g = 0; g < 4; g++) {
        int row = rowb + g;
        size_t idx = (size_t)row * ldc + col;
        float v = acc[i][j][g];
        if (EPI == 0) {
          Cz[idx] = v;
        } else if (EPI == 1) {
          Cb[idx] = (__bf16)tanhf(v + bias[col]);
        } else if (EPI == 2) {
          float t = tanhf(v + bias[col]);
          Cb[idx] = (__bf16)((1.f - t * t) * auxf[col]);
        } else if (EPI == 3) {
          float h = (float)auxb[(size_t)row * ldaux + col];
          Cb[idx] = (__bf16)(v * (1.f - h * h));
        } else {
          Cf[idx] = v + bias[col];
        }
      }
    }
  }
}

// ---------------------------------------------------------------------------
// grad = sum of 4 split-K partials; z[:, off:off+512] += coef*dt*grad; refresh zb
// ---------------------------------------------------------------------------
__global__ void update_kernel(float* __restrict__ z, __bf16* __restrict__ zb,
                              const float* __restrict__ gp,
                              const float* __restrict__ dt,
                              float coef, int off) {
  int idx = blockIdx.x * blockDim.x + threadIdx.x;  // NB*SD
  int b = idx >> 9, j = idx & 511;
  float g = gp[idx] + gp[idx + NB * SD] + gp[idx + 2 * NB * SD] +
            gp[idx + 3 * NB * SD];
  int zi = b * ZD + off + j;
  float nv = z[zi] + coef * dt[0] * g;
  z[zi] = nv;
  zb[zi] = (__bf16)nv;
}

// ---------------------------------------------------------------------------
// h_next: first 8 slices = z[:, :1024] (exact f32), rest zero
// ---------------------------------------------------------------------------
__global__ void hnext_kernel(const float* __restrict__ z,
                             float* __restrict__ out) {
  int idx = blockIdx.x * blockDim.x + threadIdx.x;  // 2048*2048
  int b = idx >> 11, i = idx & 2047;
  out[idx] = (i < 1024) ? z[b * ZD + i] : 0.f;
}

// ---------------------------------------------------------------------------
extern "C" void kernel_launch(void* const* d_in, const int* in_sizes, int n_in,
                              void* d_out, int out_size, void* d_ws,
                              size_t ws_size, hipStream_t stream) {
  const float* x        = (const float*)d_in[0];
  const float* h_padded = (const float*)d_in[1];
  const float* W1    = (const float*)d_in[3];
  const float* b1    = (const float*)d_in[4];
  const float* W2    = (const float*)d_in[5];
  const float* b2    = (const float*)d_in[6];
  const float* W3    = (const float*)d_in[7];
  const float* W_out = (const float*)d_in[9];
  const float* b_out = (const float*)d_in[10];
  const float* enc_W = (const float*)d_in[11];
  const float* enc_b = (const float*)d_in[12];
  const float* thetas = (const float*)d_in[13];
  const float* gain   = (const float*)d_in[14];
  const float* shift  = (const float*)d_in[15];
  const float* cap_p  = (const float*)d_in[16];
  const float* t_bias = (const float*)d_in[17];
  const float* l_stab = (const float*)d_in[18];

  float* out_mat  = (float*)d_out;              // (2048,1024)
  float* out_hnxt = (float*)d_out + NB * 1024;  // (2048,16,128)

  // workspace layout
  char* base = (char*)d_ws;
  float* z      = (float*)(base);                     // 16MB
  float* gpart  = (float*)(base + 16 * MB_);          // 16MB (4 x 2048x512)
  float* accp   = (float*)(base + 32 * MB_);          // scalars
  float* dtp    = accp + 1;
  __bf16* zb    = (__bf16*)(base + 32 * MB_ + 1024);  // 8MB
  __bf16* h1b   = zb + (size_t)NELEM_Z;               // 8MB
  __bf16* g2b   = h1b + (size_t)NELEM_Z;              // 8MB
  __bf16* g1b   = g2b + (size_t)NELEM_Z;              // 8MB
  __bf16* W1n   = g1b + (size_t)NELEM_Z;              // 8MB
  __bf16* W1t   = W1n + (size_t)NELEM_Z;              // 8MB
  __bf16* W2n   = W1t + (size_t)NELEM_Z;              // 8MB
  __bf16* W2t   = W2n + (size_t)NELEM_Z;              // 8MB
  __bf16* Wot   = W2t + (size_t)NELEM_Z;              // 2MB

  dim3 thr256(256);
  dim3 thrT(32, 8);

  // 1. weight conversions (independent)
  conv_f2b<<<dim3(NELEM_Z / 1024), thr256, 0, stream>>>(W1, W1n);
  conv_f2b<<<dim3(NELEM_Z / 1024), thr256, 0, stream>>>(W2, W2n);
  transpose_f2b<<<dim3(64, 64), thrT, 0, stream>>>(W1, W1t, ZD, ZD);
  transpose_f2b<<<dim3(64, 64), thrT, 0, stream>>>(W2, W2t, ZD, ZD);
  transpose_f2b<<<dim3(32, 32), thrT, 0, stream>>>(W_out, Wot, 1024, 1024);

  // 2. build z (f32 + bf16) + zero acc
  build_z_kernel<<<dim3(NELEM_Z / 256), thr256, 0, stream>>>(x, h_padded, z, zb,
                                                             accp);
  // 3. VQC -> acc ; 4. dt
  vqc_kernel<<<dim3(NB), dim3(64), 0, stream>>>(z, enc_W, enc_b, thetas, gain,
                                                shift, accp);
  dt_kernel<<<dim3(1), dim3(1), 0, stream>>>(accp, cap_p, t_bias, l_stab, dtp);

  // 5. three leapfrog gradient evaluations
  const int   j0r[3]  = {0, 512, 0};     // W1 row block (q rows / p rows)
  const int   offs[3] = {512, 0, 512};   // which half of z to update
  const float coef[3] = {-0.5f, 1.0f, -0.5f};

  dim3 gridSq(16, 16, 1);   // 2048x2048
  dim3 gridGr(4, 16, 4);    // 2048x512, split-K=4

  for (int i = 0; i < 3; i++) {
    // h1 = tanh(z @ W1 + b1)                      (bf16 out)
    mfma_gemm<1><<<gridSq, thr256, 0, stream>>>(zb, ZD, W1t, ZD, h1b, ZD, b1,
                                                nullptr, 0, ZD);
    // g2 = (1 - tanh(h1 @ W2 + b2)^2) * W3[col]   (bf16 out)
    mfma_gemm<2><<<gridSq, thr256, 0, stream>>>(h1b, ZD, W2t, ZD, g2b, ZD, b2,
                                                W3, 0, ZD);
    // g1 = (g2 @ W2^T) * (1 - h1^2)               (bf16 out)
    mfma_gemm<3><<<gridSq, thr256, 0, stream>>>(g2b, ZD, W2n, ZD, g1b, ZD,
                                                nullptr, h1b, ZD, ZD);
    // gpart[z] = g1 @ W1[j0 : j0+512, :]^T  (f32 partials, split-K=4)
    mfma_gemm<0><<<gridGr, thr256, 0, stream>>>(g1b, ZD,
                                                W1n + (size_t)j0r[i] * ZD, ZD,
                                                gpart, SD, nullptr, nullptr, 0,
                                                SD);
    // z[:, offs] += coef * dt * sum(gpart)
    update_kernel<<<dim3(NB * SD / 256), thr256, 0, stream>>>(z, zb, gpart, dtp,
                                                              coef[i], offs[i]);
  }

  // 6. out = z[:, :1024] @ W_out + b_out  (f32 out)
  mfma_gemm<4><<<dim3(8, 16, 1), thr256, 0, stream>>>(zb, ZD, Wot, 1024,
                                                      out_mat, 1024, b_out,
                                                      nullptr, 0, 1024);

  // 7. h_next writeback
  hnext_kernel<<<dim3(NELEM_Z / 256), thr256, 0, stream>>>(z, out_hnxt);
}

// Round 3
// 723.790 us; speedup vs baseline: 5.1288x; 1.1058x over previous
//
#include <hip/hip_runtime.h>
#include <math.h>

// Problem constants
#define NB 2048            // batch
#define ZD 2048            // z dim = 2*512 + 1024, also D_H
#define SD 512             // state dim
#define NELEM_Z (NB * ZD)  // 4194304
#define MB_ (1024 * 1024)

typedef float f32x4 __attribute__((ext_vector_type(4)));
typedef __bf16 bf16x8 __attribute__((ext_vector_type(8)));
typedef __bf16 bf16x4 __attribute__((ext_vector_type(4)));

__device__ __forceinline__ float softplus_f(float x) {
  if (x > 20.f) return x;
  if (x < -20.f) return expf(x);
  return log1pf(expf(x));
}

__device__ __forceinline__ void gload_lds16(const __bf16* g, __bf16* l) {
  __builtin_amdgcn_global_load_lds(
      (__attribute__((address_space(1))) void*)(g),
      (__attribute__((address_space(3))) void*)(l), 16, 0, 0);
}

// ---------------------------------------------------------------------------
// Build z = [q, p, x] (B x 2048) f32 + bf16 mirror; zero accumulator. x4 vec.
// ---------------------------------------------------------------------------
__global__ void build_z_kernel(const float* __restrict__ x,
                               const float* __restrict__ h_padded,
                               float* __restrict__ z,
                               __bf16* __restrict__ zb,
                               float* __restrict__ acc) {
  int t = blockIdx.x * blockDim.x + threadIdx.x;  // 0 .. NELEM_Z/4
  if (t == 0) acc[0] = 0.f;
  int b = t >> 9;          // 512 f32x4 per row
  int i4 = t & 511;
  f32x4 v = (i4 < 256) ? ((const f32x4*)h_padded)[t]
                       : ((const f32x4*)x)[b * 256 + (i4 - 256)];
  ((f32x4*)z)[t] = v;
  bf16x4 o;
  o[0] = (__bf16)v[0]; o[1] = (__bf16)v[1];
  o[2] = (__bf16)v[2]; o[3] = (__bf16)v[3];
  ((bf16x4*)zb)[t] = o;
}

// ---------------------------------------------------------------------------
// f32 -> bf16 flat convert (n multiple of 4*256)
// ---------------------------------------------------------------------------
__global__ void conv_f2b(const float* __restrict__ in, __bf16* __restrict__ out) {
  int i = blockIdx.x * blockDim.x + threadIdx.x;
  float4 v = ((const float4*)in)[i];
  bf16x4 o;
  o[0] = (__bf16)v.x; o[1] = (__bf16)v.y; o[2] = (__bf16)v.z; o[3] = (__bf16)v.w;
  ((bf16x4*)out)[i] = o;
}

// ---------------------------------------------------------------------------
// transpose + convert: in f32 (R x C) row-major -> out bf16 (C x R)
// block (32,8), grid (C/32, R/32)
// ---------------------------------------------------------------------------
__global__ void transpose_f2b(const float* __restrict__ in,
                              __bf16* __restrict__ out, int R, int C) {
  __shared__ float tile[32][33];
  int bx = blockIdx.x * 32, by = blockIdx.y * 32;
  int tx = threadIdx.x, ty = threadIdx.y;
  for (int r = ty; r < 32; r += 8)
    tile[r][tx] = in[(size_t)(by + r) * C + bx + tx];
  __syncthreads();
  for (int r = ty; r < 32; r += 8)
    out[(size_t)(bx + r) * R + by + tx] = (__bf16)tile[tx][r];
}

// ---------------------------------------------------------------------------
// VQC: one 64-thread block per batch row (dt saturates; precision-forgiving).
// ---------------------------------------------------------------------------
__global__ void vqc_kernel(const float* __restrict__ z,
                           const float* __restrict__ enc_W,  // (2048,6)
                           const float* __restrict__ enc_b,  // (6,)
                           const float* __restrict__ thetas, // (3,6)
                           const float* __restrict__ gain,
                           const float* __restrict__ shift,
                           float* __restrict__ acc) {
  int b = blockIdx.x;
  int lane = threadIdx.x;  // 0..63
  const float* zb = z + (size_t)b * ZD;

  float pa[6] = {0.f, 0.f, 0.f, 0.f, 0.f, 0.f};
  for (int j = lane; j < 2048; j += 64) {
    float c = (j < 1024) ? zb[1024 + j] : zb[j - 1024];
    const float* w = enc_W + j * 6;
#pragma unroll
    for (int k = 0; k < 6; k++) pa[k] += c * w[k];
  }
#pragma unroll
  for (int k = 0; k < 6; k++) {
    for (int off = 32; off > 0; off >>= 1) pa[k] += __shfl_down(pa[k], off, 64);
    pa[k] = __shfl(pa[k], 0, 64) + enc_b[k];
  }

  float s = (lane == 0) ? 1.f : 0.f;
  int rot = ((lane << 1) | (lane >> 5)) & 63;
  float cz = (__popc(lane & rot) & 1) ? -1.f : 1.f;

#pragma unroll
  for (int k = 0; k < 6; k++) {
    float half = 0.5f * pa[k];
    float c = cosf(half), si = sinf(half);
    int m = 1 << (5 - k);
    float other = __shfl_xor(s, m, 64);
    s = (lane & m) ? (si * other + c * s) : (c * s - si * other);
  }
  for (int l = 0; l < 3; l++) {
#pragma unroll
    for (int k = 0; k < 6; k++) {
      float half = 0.5f * thetas[l * 6 + k];
      float c = cosf(half), si = sinf(half);
      int m = 1 << (5 - k);
      float other = __shfl_xor(s, m, 64);
      s = (lane & m) ? (si * other + c * s) : (c * s - si * other);
    }
    s *= cz;
  }

  float zobs = (6.f - 2.f * (float)__popc(lane)) * (1.f / 6.f);
  float val = s * s * zobs;
  for (int off = 32; off > 0; off >>= 1) val += __shfl_down(val, off, 64);

  if (lane == 0) {
    float sg = softplus_f(gain[0]);
    float ss = softplus_f(shift[0]);
    atomicAdd(acc, softplus_f(sg * val - ss));
  }
}

// ---------------------------------------------------------------------------
// dt scalar chain
// ---------------------------------------------------------------------------
__global__ void dt_kernel(const float* __restrict__ acc,
                          const float* __restrict__ cap_param,
                          const float* __restrict__ time_bias,
                          const float* __restrict__ last_stable,
                          float* __restrict__ dt_out) {
  float raw = acc[0] * (1.f / (float)NB) + time_bias[0];
  float cap = fmaxf(softplus_f(cap_param[0]), 1e-6f);
  float evo = cap / (1.f + expf(-raw / cap));
  if (!isfinite(evo)) evo = cap / (1.f + expf(-time_bias[0] / cap));
  float prev = fmaxf(last_stable[0], 1e-6f);
  float cand = fmaxf(evo, 1e-6f);
  float max_step = fmaxf(prev * 0.1f, 1e-4f);
  cand = fminf(cand, prev + max_step);
  cand = fminf(cand, 0.05f);
  dt_out[0] = isfinite(cand) ? cand : prev;
}

// ---------------------------------------------------------------------------
// MFMA bf16 GEMM: C[M,N] = epi( A[M,K] @ Bt[N,K]^T )
// Tile (64*WM) x (64*WN), WM*WN waves (each wave 64x64: 4x4 of 16x16x32 MFMA).
// Double-buffered LDS, single __syncthreads per K-iter: tile k+1 is staged
// (global_load_lds w16) into the other buffer BEFORE the MFMA phase of tile k,
// so the barrier's vmcnt(0) drain overlaps a full MFMA phase.
// XOR chunk swizzle: chunk (row m, k-octet o) at index m*4 + (o^((m+m>>2)&3))
//  -> 64B-coalesced staging AND <=2-way-conflict ds_read_b128 fragment reads.
// EPI: 0 f32 split-K partial | 1 bf16 tanh(v+bias[col])
//      2 bf16 (1-t^2)*auxf[col] | 3 bf16 v*(1-h^2), h=auxb[row,col]
//      4 f32 v+bias[col]
// ---------------------------------------------------------------------------
template <int EPI, int WM, int WN>
__global__ __launch_bounds__(64 * WM * WN) void mfma_gemm(
    const __bf16* __restrict__ A, int lda,
    const __bf16* __restrict__ Bt, int ldb,
    void* __restrict__ Cv, int ldc,
    const float* __restrict__ bias,
    const void* __restrict__ aux, int ldaux,
    int Kslice) {
  constexpr int BM = 64 * WM, BN = 64 * WN;
  constexpr int NT = 64 * WM * WN;
  constexpr int NCA = BM * 4 / NT;  // A chunks per thread
  constexpr int NCB = BN * 4 / NT;  // B chunks per thread
  __shared__ __bf16 sA[2][BM * 32];
  __shared__ __bf16 sB[2][BN * 32];

  const int tid = threadIdx.x;
  const int lane = tid & 63;
  const int w = tid >> 6;
  const int wm = w % WM, wn = w / WM;
  const int row0 = blockIdx.y * BM;
  const int col0 = blockIdx.x * BN;
  const int koff = blockIdx.z * Kslice;

  // --- staging chunk assignment (global ptr + LDS offset, k0-invariant) ---
  const __bf16* gA[NCA]; int lAo[NCA];
  const __bf16* gB[NCB]; int lBo[NCB];
#pragma unroll
  for (int i = 0; i < NCA; i++) {
    int c = i * NT + tid;
    int m = c >> 2, o = (c & 3) ^ ((m + (m >> 2)) & 3);
    gA[i] = A + (size_t)(row0 + m) * lda + koff + o * 8;
    lAo[i] = c * 8;
  }
#pragma unroll
  for (int i = 0; i < NCB; i++) {
    int c = i * NT + tid;
    int m = c >> 2, o = (c & 3) ^ ((m + (m >> 2)) & 3);
    gB[i] = Bt + (size_t)(col0 + m) * ldb + koff + o * 8;
    lBo[i] = c * 8;
  }

  // --- fragment LDS offsets ---
  const int q = lane >> 4, r = lane & 15;
  int aoff[4], boff[4];
#pragma unroll
  for (int i = 0; i < 4; i++) {
    int ma = wm * 64 + i * 16 + r;
    aoff[i] = (ma * 4 + (q ^ ((ma + (ma >> 2)) & 3))) * 8;
    int mb = wn * 64 + i * 16 + r;
    boff[i] = (mb * 4 + (q ^ ((mb + (mb >> 2)) & 3))) * 8;
  }

  f32x4 acc[4][4] = {};

  // prefetch tile 0 into buf 0
#pragma unroll
  for (int i = 0; i < NCA; i++) gload_lds16(gA[i], &sA[0][0] + lAo[i]);
#pragma unroll
  for (int i = 0; i < NCB; i++) gload_lds16(gB[i], &sB[0][0] + lBo[i]);

  int cur = 0;
  for (int k0 = 0; k0 < Kslice; k0 += 32) {
    __syncthreads();  // tile-k landed (vmcnt drain); prev-iter LDS reads done

    if (k0 + 32 < Kslice) {  // stage tile k+1 into other buffer
      int nxt = cur ^ 1;
#pragma unroll
      for (int i = 0; i < NCA; i++)
        gload_lds16(gA[i] + k0 + 32, &sA[nxt][0] + lAo[i]);
#pragma unroll
      for (int i = 0; i < NCB; i++)
        gload_lds16(gB[i] + k0 + 32, &sB[nxt][0] + lBo[i]);
    }

    bf16x8 af[4], bfv[4];
#pragma unroll
    for (int i = 0; i < 4; i++) af[i] = *(const bf16x8*)(&sA[cur][0] + aoff[i]);
#pragma unroll
    for (int j = 0; j < 4; j++) bfv[j] = *(const bf16x8*)(&sB[cur][0] + boff[j]);
#pragma unroll
    for (int i = 0; i < 4; i++)
#pragma unroll
      for (int j = 0; j < 4; j++)
        acc[i][j] = __builtin_amdgcn_mfma_f32_16x16x32_bf16(af[i], bfv[j],
                                                            acc[i][j], 0, 0, 0);
    cur ^= 1;
  }

  // --- epilogue: C/D layout col=lane&15, row=(lane>>4)*4+reg ---
  float* Cf = (float*)Cv;
  __bf16* Cb = (__bf16*)Cv;
  const float* auxf = (const float*)aux;
  const __bf16* auxb = (const __bf16*)aux;
  float* Cz = Cf + (size_t)blockIdx.z * (size_t)gridDim.y * BM * ldc;

#pragma unroll
  for (int i = 0; i < 4; i++) {
    int rowb = row0 + wm * 64 + i * 16 + q * 4;
#pragma unroll
    for (int j = 0; j < 4; j++) {
      int col = col0 + wn * 64 + j * 16 + r;
#pragma unroll
      for (int g = 0; g < 4; g++) {
        int row = rowb + g;
        size_t idx = (size_t)row * ldc + col;
        float v = acc[i][j][g];
        if (EPI == 0) {
          Cz[idx] = v;
        } else if (EPI == 1) {
          Cb[idx] = (__bf16)tanhf(v + bias[col]);
        } else if (EPI == 2) {
          float t = tanhf(v + bias[col]);
          Cb[idx] = (__bf16)((1.f - t * t) * auxf[col]);
        } else if (EPI == 3) {
          float h = (float)auxb[(size_t)row * ldaux + col];
          Cb[idx] = (__bf16)(v * (1.f - h * h));
        } else {
          Cf[idx] = v + bias[col];
        }
      }
    }
  }
}

// ---------------------------------------------------------------------------
// grad = sum of 4 split-K partials; z[:, off:off+512] += coef*dt*grad (x4 vec)
// ---------------------------------------------------------------------------
__global__ void update_kernel(float* __restrict__ z, __bf16* __restrict__ zb,
                              const float* __restrict__ gp,
                              const float* __restrict__ dt,
                              float coef, int off) {
  int t = blockIdx.x * blockDim.x + threadIdx.x;  // 0 .. NB*SD/4
  int b = t >> 7;  // 128 f32x4 per row
  int j4 = t & 127;
  const f32x4* g4 = (const f32x4*)gp;
  constexpr int STRIDE = NB * SD / 4;
  f32x4 g = g4[t] + g4[t + STRIDE] + g4[t + 2 * STRIDE] + g4[t + 3 * STRIDE];
  int zi4 = (b * ZD + off) / 4 + j4;
  f32x4 v = ((f32x4*)z)[zi4];
  float s = coef * dt[0];
  v[0] += s * g[0]; v[1] += s * g[1]; v[2] += s * g[2]; v[3] += s * g[3];
  ((f32x4*)z)[zi4] = v;
  bf16x4 o;
  o[0] = (__bf16)v[0]; o[1] = (__bf16)v[1];
  o[2] = (__bf16)v[2]; o[3] = (__bf16)v[3];
  ((bf16x4*)zb)[zi4] = o;
}

// ---------------------------------------------------------------------------
// h_next: first 8 slices = z[:, :1024] (exact f32), rest zero (x4 vec)
// ---------------------------------------------------------------------------
__global__ void hnext_kernel(const float* __restrict__ z,
                             float* __restrict__ out) {
  int t = blockIdx.x * blockDim.x + threadIdx.x;  // 0 .. NELEM_Z/4
  int i4 = t & 511;
  f32x4 zero = {0.f, 0.f, 0.f, 0.f};
  ((f32x4*)out)[t] = (i4 < 256) ? ((const f32x4*)z)[t] : zero;
}

// ---------------------------------------------------------------------------
extern "C" void kernel_launch(void* const* d_in, const int* in_sizes, int n_in,
                              void* d_out, int out_size, void* d_ws,
                              size_t ws_size, hipStream_t stream) {
  const float* x        = (const float*)d_in[0];
  const float* h_padded = (const float*)d_in[1];
  const float* W1    = (const float*)d_in[3];
  const float* b1    = (const float*)d_in[4];
  const float* W2    = (const float*)d_in[5];
  const float* b2    = (const float*)d_in[6];
  const float* W3    = (const float*)d_in[7];
  const float* W_out = (const float*)d_in[9];
  const float* b_out = (const float*)d_in[10];
  const float* enc_W = (const float*)d_in[11];
  const float* enc_b = (const float*)d_in[12];
  const float* thetas = (const float*)d_in[13];
  const float* gain   = (const float*)d_in[14];
  const float* shift  = (const float*)d_in[15];
  const float* cap_p  = (const float*)d_in[16];
  const float* t_bias = (const float*)d_in[17];
  const float* l_stab = (const float*)d_in[18];

  float* out_mat  = (float*)d_out;              // (2048,1024)
  float* out_hnxt = (float*)d_out + NB * 1024;  // (2048,16,128)

  // workspace layout
  char* base = (char*)d_ws;
  float* z      = (float*)(base);                     // 16MB
  float* gpart  = (float*)(base + 16 * MB_);          // 16MB (4 x 2048x512)
  float* accp   = (float*)(base + 32 * MB_);          // scalars
  float* dtp    = accp + 1;
  __bf16* zb    = (__bf16*)(base + 32 * MB_ + 1024);  // 8MB
  __bf16* h1b   = zb + (size_t)NELEM_Z;               // 8MB
  __bf16* g2b   = h1b + (size_t)NELEM_Z;              // 8MB
  __bf16* g1b   = g2b + (size_t)NELEM_Z;              // 8MB
  __bf16* W1n   = g1b + (size_t)NELEM_Z;              // 8MB
  __bf16* W1t   = W1n + (size_t)NELEM_Z;              // 8MB
  __bf16* W2n   = W1t + (size_t)NELEM_Z;              // 8MB
  __bf16* W2t   = W2n + (size_t)NELEM_Z;              // 8MB
  __bf16* Wot   = W2t + (size_t)NELEM_Z;              // 2MB

  dim3 thr256(256);
  dim3 thr128(128);
  dim3 thrT(32, 8);

  // 1. weight conversions (independent)
  conv_f2b<<<dim3(NELEM_Z / 1024), thr256, 0, stream>>>(W1, W1n);
  conv_f2b<<<dim3(NELEM_Z / 1024), thr256, 0, stream>>>(W2, W2n);
  transpose_f2b<<<dim3(64, 64), thrT, 0, stream>>>(W1, W1t, ZD, ZD);
  transpose_f2b<<<dim3(64, 64), thrT, 0, stream>>>(W2, W2t, ZD, ZD);
  transpose_f2b<<<dim3(32, 32), thrT, 0, stream>>>(W_out, Wot, 1024, 1024);

  // 2. build z (f32 + bf16) + zero acc
  build_z_kernel<<<dim3(NELEM_Z / 4 / 256), thr256, 0, stream>>>(x, h_padded, z,
                                                                 zb, accp);
  // 3. VQC -> acc ; 4. dt
  vqc_kernel<<<dim3(NB), dim3(64), 0, stream>>>(z, enc_W, enc_b, thetas, gain,
                                                shift, accp);
  dt_kernel<<<dim3(1), dim3(1), 0, stream>>>(accp, cap_p, t_bias, l_stab, dtp);

  // 5. three leapfrog gradient evaluations
  const int   j0r[3]  = {0, 512, 0};     // W1 row block (q rows / p rows)
  const int   offs[3] = {512, 0, 512};   // which half of z to update
  const float coef[3] = {-0.5f, 1.0f, -0.5f};

  dim3 gridSq(32, 16, 1);   // 2048x2048, 128x64 tiles -> 512 blocks
  dim3 gridGr(8, 16, 4);    // 2048x512, split-K=4     -> 512 blocks

  for (int i = 0; i < 3; i++) {
    // h1 = tanh(z @ W1 + b1)                      (bf16 out)
    mfma_gemm<1, 2, 1><<<gridSq, thr128, 0, stream>>>(zb, ZD, W1t, ZD, h1b, ZD,
                                                      b1, nullptr, 0, ZD);
    // g2 = (1 - tanh(h1 @ W2 + b2)^2) * W3[col]   (bf16 out)
    mfma_gemm<2, 2, 1><<<gridSq, thr128, 0, stream>>>(h1b, ZD, W2t, ZD, g2b, ZD,
                                                      b2, W3, 0, ZD);
    // g1 = (g2 @ W2^T) * (1 - h1^2)               (bf16 out)
    mfma_gemm<3, 2, 1><<<gridSq, thr128, 0, stream>>>(g2b, ZD, W2n, ZD, g1b, ZD,
                                                      nullptr, h1b, ZD, ZD);
    // gpart[z] = g1 @ W1[j0 : j0+512, :]^T  (f32 partials, split-K=4)
    mfma_gemm<0, 2, 1><<<gridGr, thr128, 0, stream>>>(
        g1b, ZD, W1n + (size_t)j0r[i] * ZD, ZD, gpart, SD, nullptr, nullptr, 0,
        SD);
    // z[:, offs] += coef * dt * sum(gpart)
    update_kernel<<<dim3(NB * SD / 4 / 256), thr256, 0, stream>>>(
        z, zb, gpart, dtp, coef[i], offs[i]);
  }

  // 6. out = z[:, :1024] @ W_out + b_out  (f32 out, 128x64 tiles, 256 blocks)
  mfma_gemm<4, 2, 1><<<dim3(16, 16, 1), thr128, 0, stream>>>(
      zb, ZD, Wot, 1024, out_mat, 1024, b_out, nullptr, 0, 1024);

  // 7. h_next writeback
  hnext_kernel<<<dim3(NELEM_Z / 4 / 256), thr256, 0, stream>>>(z, out_hnxt);
}

// Round 4
// 623.637 us; speedup vs baseline: 5.9525x; 1.1606x over previous
//
#include <hip/hip_runtime.h>
#include <math.h>

// Problem constants
#define NB 2048            // batch
#define ZD 2048            // z dim = 2*512 + 1024, also D_H
#define SD 512             // state dim
#define NELEM_Z (NB * ZD)  // 4194304
#define MB_ (1024 * 1024)

typedef float f32x4 __attribute__((ext_vector_type(4)));
typedef __bf16 bf16x8 __attribute__((ext_vector_type(8)));
typedef __bf16 bf16x4 __attribute__((ext_vector_type(4)));

__device__ __forceinline__ float softplus_f(float x) {
  if (x > 20.f) return x;
  if (x < -20.f) return expf(x);
  return log1pf(expf(x));
}

__device__ __forceinline__ void gload_lds16(const __bf16* g, __bf16* l) {
  __builtin_amdgcn_global_load_lds(
      (__attribute__((address_space(1))) void*)(g),
      (__attribute__((address_space(3))) void*)(l), 16, 0, 0);
}

// ---------------------------------------------------------------------------
// Build z = [q, p, x] (B x 2048) f32 + bf16 mirror; zero accumulator. x4 vec.
// ---------------------------------------------------------------------------
__global__ void build_z_kernel(const float* __restrict__ x,
                               const float* __restrict__ h_padded,
                               float* __restrict__ z,
                               __bf16* __restrict__ zb,
                               float* __restrict__ acc) {
  int t = blockIdx.x * blockDim.x + threadIdx.x;  // 0 .. NELEM_Z/4
  if (t == 0) acc[0] = 0.f;
  int b = t >> 9;          // 512 f32x4 per row
  int i4 = t & 511;
  f32x4 v = (i4 < 256) ? ((const f32x4*)h_padded)[t]
                       : ((const f32x4*)x)[b * 256 + (i4 - 256)];
  ((f32x4*)z)[t] = v;
  bf16x4 o;
  o[0] = (__bf16)v[0]; o[1] = (__bf16)v[1];
  o[2] = (__bf16)v[2]; o[3] = (__bf16)v[3];
  ((bf16x4*)zb)[t] = o;
}

// ---------------------------------------------------------------------------
// Weight prep: in f32 (R x C) -> outN bf16 (R x C, straight, optional) and
// outT bf16 (C x R, transposed). block (32,8), grid (C/32, R/32)
// ---------------------------------------------------------------------------
__global__ void prep_w(const float* __restrict__ in,
                       __bf16* __restrict__ outN,
                       __bf16* __restrict__ outT, int R, int C) {
  __shared__ float tile[32][33];
  int bx = blockIdx.x * 32, by = blockIdx.y * 32;
  int tx = threadIdx.x, ty = threadIdx.y;
  for (int r = ty; r < 32; r += 8) {
    float v = in[(size_t)(by + r) * C + bx + tx];
    tile[r][tx] = v;
    if (outN) outN[(size_t)(by + r) * C + bx + tx] = (__bf16)v;
  }
  __syncthreads();
  for (int r = ty; r < 32; r += 8)
    outT[(size_t)(bx + r) * R + by + tx] = (__bf16)tile[tx][r];
}

// ---------------------------------------------------------------------------
// VQC: one 256-thread block (4 waves) per batch row. Waves split the 2048-j
// angle dot-product; LDS reduce; wave 0 runs the 64-amplitude sim.
// ctrl[j] = (j<1024) ? z[b][1024+j] : z[b][j-1024]
// ---------------------------------------------------------------------------
__global__ __launch_bounds__(256) void vqc_kernel(
    const float* __restrict__ z,
    const float* __restrict__ enc_W,  // (2048,6)
    const float* __restrict__ enc_b,  // (6,)
    const float* __restrict__ thetas, // (3,6)
    const float* __restrict__ gain,
    const float* __restrict__ shift,
    float* __restrict__ acc) {
  int b = blockIdx.x;
  int lane = threadIdx.x & 63;
  int w = threadIdx.x >> 6;  // 0..3
  const float* zrow = z + (size_t)b * ZD;
  __shared__ float red[4][6];

  float pa[6] = {0.f, 0.f, 0.f, 0.f, 0.f, 0.f};
  int j0 = w * 512;
#pragma unroll
  for (int t = 0; t < 8; t++) {
    int j = j0 + t * 64 + lane;
    float c = (j < 1024) ? zrow[1024 + j] : zrow[j - 1024];
    const float* wp = enc_W + j * 6;
#pragma unroll
    for (int k = 0; k < 6; k++) pa[k] += c * wp[k];
  }
#pragma unroll
  for (int k = 0; k < 6; k++)
    for (int off = 32; off > 0; off >>= 1) pa[k] += __shfl_down(pa[k], off, 64);
  if (lane == 0) {
#pragma unroll
    for (int k = 0; k < 6; k++) red[w][k] = pa[k];
  }
  __syncthreads();

  if (w == 0) {
    float ang[6];
#pragma unroll
    for (int k = 0; k < 6; k++)
      ang[k] = red[0][k] + red[1][k] + red[2][k] + red[3][k] + enc_b[k];

    float s = (lane == 0) ? 1.f : 0.f;
    int rot = ((lane << 1) | (lane >> 5)) & 63;
    float cz = (__popc(lane & rot) & 1) ? -1.f : 1.f;

#pragma unroll
    for (int k = 0; k < 6; k++) {
      float half = 0.5f * ang[k];
      float c = cosf(half), si = sinf(half);
      int m = 1 << (5 - k);
      float other = __shfl_xor(s, m, 64);
      s = (lane & m) ? (si * other + c * s) : (c * s - si * other);
    }
    for (int l = 0; l < 3; l++) {
#pragma unroll
      for (int k = 0; k < 6; k++) {
        float half = 0.5f * thetas[l * 6 + k];
        float c = cosf(half), si = sinf(half);
        int m = 1 << (5 - k);
        float other = __shfl_xor(s, m, 64);
        s = (lane & m) ? (si * other + c * s) : (c * s - si * other);
      }
      s *= cz;
    }

    float zobs = (6.f - 2.f * (float)__popc(lane)) * (1.f / 6.f);
    float val = s * s * zobs;
    for (int off = 32; off > 0; off >>= 1) val += __shfl_down(val, off, 64);

    if (lane == 0) {
      float sg = softplus_f(gain[0]);
      float ss = softplus_f(shift[0]);
      atomicAdd(acc, softplus_f(sg * val - ss));
    }
  }
}

// ---------------------------------------------------------------------------
// dt scalar chain
// ---------------------------------------------------------------------------
__global__ void dt_kernel(const float* __restrict__ acc,
                          const float* __restrict__ cap_param,
                          const float* __restrict__ time_bias,
                          const float* __restrict__ last_stable,
                          float* __restrict__ dt_out) {
  float raw = acc[0] * (1.f / (float)NB) + time_bias[0];
  float cap = fmaxf(softplus_f(cap_param[0]), 1e-6f);
  float evo = cap / (1.f + expf(-raw / cap));
  if (!isfinite(evo)) evo = cap / (1.f + expf(-time_bias[0] / cap));
  float prev = fmaxf(last_stable[0], 1e-6f);
  float cand = fmaxf(evo, 1e-6f);
  float max_step = fmaxf(prev * 0.1f, 1e-4f);
  cand = fminf(cand, prev + max_step);
  cand = fminf(cand, 0.05f);
  dt_out[0] = isfinite(cand) ? cand : prev;
}

// ---------------------------------------------------------------------------
// MFMA bf16 GEMM: C[M,N] = epi( A[M,K] @ Bt[N,K]^T )
// Block tile 128x128, BK=64, 512 threads = 8 waves (wave-tile 64x32:
// wm=w&1 row half, wn=w>>1 col quarter), 16x16x32 MFMA, double-buffered LDS,
// one __syncthreads per K-iter; prefetch of tile k+1 issued before the MFMA
// phase of tile k (full-iteration latency coverage, 8 waves/CU TLP).
// LDS chunk layout: storage chunk index c = m*8 + cc holds global k-octet
// o = cc ^ ((m + m>>2) & 7)  -> 128B-coalesced staging (gload_lds lane rule)
// AND near-conflict-free ds_read_b128 fragment reads.
// EPI: 0 f32 split-K partial | 1 bf16 tanh(v+bias[col])
//      2 bf16 (1-t^2)*auxf[col] | 3 bf16 v*(1-h^2), h=auxb[row,col]
// ---------------------------------------------------------------------------
template <int EPI>
__global__ __launch_bounds__(512) void mfma_gemm(
    const __bf16* __restrict__ A, int lda,
    const __bf16* __restrict__ Bt, int ldb,
    void* __restrict__ Cv, int ldc,
    const float* __restrict__ bias,
    const void* __restrict__ aux, int ldaux,
    int Kslice) {
  __shared__ __bf16 sA[2][128 * 64];
  __shared__ __bf16 sB[2][128 * 64];

  const int tid = threadIdx.x;
  const int lane = tid & 63;
  const int w = tid >> 6;            // 0..7
  const int wm = w & 1, wn = w >> 1; // wave-tile: rows wm*64+, cols wn*32+
  const int row0 = blockIdx.y * 128;
  const int col0 = blockIdx.x * 128;
  const int koff = blockIdx.z * Kslice;

  // --- staging assignment: 2 A-chunks + 2 B-chunks per thread per tile ---
  const __bf16* gA[2]; const __bf16* gB[2]; int lof[2];
#pragma unroll
  for (int i = 0; i < 2; i++) {
    int c = i * 512 + tid;
    int m = c >> 3, cc = c & 7;
    int o = cc ^ ((m + (m >> 2)) & 7);
    gA[i] = A + (size_t)(row0 + m) * lda + koff + o * 8;
    gB[i] = Bt + (size_t)(col0 + m) * ldb + koff + o * 8;
    lof[i] = c * 8;
  }

  // --- fragment LDS offsets (k0-invariant) ---
  const int q = lane >> 4, r = lane & 15;
  int aoff[4][2], boff[2][2];
#pragma unroll
  for (int i = 0; i < 4; i++) {
    int ma = wm * 64 + i * 16 + r;
    int s = (ma + (ma >> 2)) & 7;
#pragma unroll
    for (int h = 0; h < 2; h++)
      aoff[i][h] = (ma * 8 + ((h * 4 + q) ^ s)) * 8;
  }
#pragma unroll
  for (int j = 0; j < 2; j++) {
    int mb = wn * 32 + j * 16 + r;
    int s = (mb + (mb >> 2)) & 7;
#pragma unroll
    for (int h = 0; h < 2; h++)
      boff[j][h] = (mb * 8 + ((h * 4 + q) ^ s)) * 8;
  }

  f32x4 acc[4][2] = {};

  // prefetch tile 0 into buf 0
#pragma unroll
  for (int i = 0; i < 2; i++) gload_lds16(gA[i], &sA[0][0] + lof[i]);
#pragma unroll
  for (int i = 0; i < 2; i++) gload_lds16(gB[i], &sB[0][0] + lof[i]);

  int cur = 0;
  for (int k0 = 0; k0 < Kslice; k0 += 64) {
    __syncthreads();  // tile-k landed (vmcnt drain); prev-iter LDS reads done

    if (k0 + 64 < Kslice) {  // stage tile k+1 into other buffer
      int nxt = cur ^ 1;
#pragma unroll
      for (int i = 0; i < 2; i++)
        gload_lds16(gA[i] + k0 + 64, &sA[nxt][0] + lof[i]);
#pragma unroll
      for (int i = 0; i < 2; i++)
        gload_lds16(gB[i] + k0 + 64, &sB[nxt][0] + lof[i]);
    }

    bf16x8 af[4][2], bfr[2][2];
#pragma unroll
    for (int i = 0; i < 4; i++)
#pragma unroll
      for (int h = 0; h < 2; h++)
        af[i][h] = *(const bf16x8*)(&sA[cur][0] + aoff[i][h]);
#pragma unroll
    for (int j = 0; j < 2; j++)
#pragma unroll
      for (int h = 0; h < 2; h++)
        bfr[j][h] = *(const bf16x8*)(&sB[cur][0] + boff[j][h]);
#pragma unroll
    for (int h = 0; h < 2; h++)
#pragma unroll
      for (int i = 0; i < 4; i++)
#pragma unroll
        for (int j = 0; j < 2; j++)
          acc[i][j] = __builtin_amdgcn_mfma_f32_16x16x32_bf16(
              af[i][h], bfr[j][h], acc[i][j], 0, 0, 0);
    cur ^= 1;
  }

  // --- epilogue: C/D layout col=lane&15, row=(lane>>4)*4+reg ---
  float* Cf = (float*)Cv;
  __bf16* Cb = (__bf16*)Cv;
  const float* auxf = (const float*)aux;
  const __bf16* auxb = (const __bf16*)aux;
  float* Cz = Cf + (size_t)blockIdx.z * (size_t)gridDim.y * 128 * ldc;

#pragma unroll
  for (int i = 0; i < 4; i++) {
    int rowb = row0 + wm * 64 + i * 16 + q * 4;
#pragma unroll
    for (int j = 0; j < 2; j++) {
      int col = col0 + wn * 32 + j * 16 + r;
#pragma unroll
      for (int g = 0; g < 4; g++) {
        int row = rowb + g;
        size_t idx = (size_t)row * ldc + col;
        float v = acc[i][j][g];
        if (EPI == 0) {
          Cz[idx] = v;
        } else if (EPI == 1) {
          Cb[idx] = (__bf16)tanhf(v + bias[col]);
        } else if (EPI == 2) {
          float t = tanhf(v + bias[col]);
          Cb[idx] = (__bf16)((1.f - t * t) * auxf[col]);
        } else {
          float h = (float)auxb[(size_t)row * ldaux + col];
          Cb[idx] = (__bf16)(v * (1.f - h * h));
        }
      }
    }
  }
}

// ---------------------------------------------------------------------------
// grad = sum of 4 split-K partials; z[:, off:off+512] += coef*dt*grad (x4 vec)
// ---------------------------------------------------------------------------
__global__ void update_kernel(float* __restrict__ z, __bf16* __restrict__ zb,
                              const float* __restrict__ gp,
                              const float* __restrict__ dt,
                              float coef, int off) {
  int t = blockIdx.x * blockDim.x + threadIdx.x;  // 0 .. NB*SD/4
  int b = t >> 7;  // 128 f32x4 per row
  int j4 = t & 127;
  const f32x4* g4 = (const f32x4*)gp;
  constexpr int STRIDE = NB * SD / 4;
  f32x4 g = g4[t] + g4[t + STRIDE] + g4[t + 2 * STRIDE] + g4[t + 3 * STRIDE];
  int zi4 = (b * ZD + off) / 4 + j4;
  f32x4 v = ((f32x4*)z)[zi4];
  float s = coef * dt[0];
  v[0] += s * g[0]; v[1] += s * g[1]; v[2] += s * g[2]; v[3] += s * g[3];
  ((f32x4*)z)[zi4] = v;
  bf16x4 o;
  o[0] = (__bf16)v[0]; o[1] = (__bf16)v[1];
  o[2] = (__bf16)v[2]; o[3] = (__bf16)v[3];
  ((bf16x4*)zb)[zi4] = o;
}

// ---------------------------------------------------------------------------
// W_out split-K=2 reduce + bias: out[b,c] = p0 + p1 + b_out[c]  (f32, x4 vec)
// ---------------------------------------------------------------------------
__global__ void wout_reduce(const float* __restrict__ gp,
                            const float* __restrict__ b_out,
                            float* __restrict__ out) {
  int t = blockIdx.x * blockDim.x + threadIdx.x;  // 0 .. NB*1024/4
  constexpr int S = NB * 1024 / 4;
  const f32x4* g4 = (const f32x4*)gp;
  f32x4 v = g4[t] + g4[t + S];
  f32x4 bb = ((const f32x4*)b_out)[t & 255];
  v[0] += bb[0]; v[1] += bb[1]; v[2] += bb[2]; v[3] += bb[3];
  ((f32x4*)out)[t] = v;
}

// ---------------------------------------------------------------------------
// h_next: first 8 slices = z[:, :1024] (exact f32), rest zero (x4 vec)
// ---------------------------------------------------------------------------
__global__ void hnext_kernel(const float* __restrict__ z,
                             float* __restrict__ out) {
  int t = blockIdx.x * blockDim.x + threadIdx.x;  // 0 .. NELEM_Z/4
  int i4 = t & 511;
  f32x4 zero = {0.f, 0.f, 0.f, 0.f};
  ((f32x4*)out)[t] = (i4 < 256) ? ((const f32x4*)z)[t] : zero;
}

// ---------------------------------------------------------------------------
extern "C" void kernel_launch(void* const* d_in, const int* in_sizes, int n_in,
                              void* d_out, int out_size, void* d_ws,
                              size_t ws_size, hipStream_t stream) {
  const float* x        = (const float*)d_in[0];
  const float* h_padded = (const float*)d_in[1];
  const float* W1    = (const float*)d_in[3];
  const float* b1    = (const float*)d_in[4];
  const float* W2    = (const float*)d_in[5];
  const float* b2    = (const float*)d_in[6];
  const float* W3    = (const float*)d_in[7];
  const float* W_out = (const float*)d_in[9];
  const float* b_out = (const float*)d_in[10];
  const float* enc_W = (const float*)d_in[11];
  const float* enc_b = (const float*)d_in[12];
  const float* thetas = (const float*)d_in[13];
  const float* gain   = (const float*)d_in[14];
  const float* shift  = (const float*)d_in[15];
  const float* cap_p  = (const float*)d_in[16];
  const float* t_bias = (const float*)d_in[17];
  const float* l_stab = (const float*)d_in[18];

  float* out_mat  = (float*)d_out;              // (2048,1024)
  float* out_hnxt = (float*)d_out + NB * 1024;  // (2048,16,128)

  // workspace layout
  char* base = (char*)d_ws;
  float* z      = (float*)(base);                     // 16MB
  float* gpart  = (float*)(base + 16 * MB_);          // 16MB (4x 2048x512 f32
                                                      //  or 2x 2048x1024 f32)
  float* accp   = (float*)(base + 32 * MB_);          // scalars
  float* dtp    = accp + 1;
  __bf16* zb    = (__bf16*)(base + 32 * MB_ + 1024);  // 8MB
  __bf16* h1b   = zb + (size_t)NELEM_Z;               // 8MB
  __bf16* g2b   = h1b + (size_t)NELEM_Z;              // 8MB
  __bf16* g1b   = g2b + (size_t)NELEM_Z;              // 8MB
  __bf16* W1n   = g1b + (size_t)NELEM_Z;              // 8MB
  __bf16* W1t   = W1n + (size_t)NELEM_Z;              // 8MB
  __bf16* W2n   = W1t + (size_t)NELEM_Z;              // 8MB
  __bf16* W2t   = W2n + (size_t)NELEM_Z;              // 8MB
  __bf16* Wot   = W2t + (size_t)NELEM_Z;              // 2MB

  dim3 thr256(256);
  dim3 thr512(512);
  dim3 thrT(32, 8);

  // 1. weight prep (convert + transpose fused)
  prep_w<<<dim3(64, 64), thrT, 0, stream>>>(W1, W1n, W1t, ZD, ZD);
  prep_w<<<dim3(64, 64), thrT, 0, stream>>>(W2, W2n, W2t, ZD, ZD);
  prep_w<<<dim3(32, 32), thrT, 0, stream>>>(W_out, nullptr, Wot, 1024, 1024);

  // 2. build z (f32 + bf16) + zero acc
  build_z_kernel<<<dim3(NELEM_Z / 4 / 256), thr256, 0, stream>>>(x, h_padded, z,
                                                                 zb, accp);
  // 3. VQC -> acc ; 4. dt
  vqc_kernel<<<dim3(NB), thr256, 0, stream>>>(z, enc_W, enc_b, thetas, gain,
                                              shift, accp);
  dt_kernel<<<dim3(1), dim3(1), 0, stream>>>(accp, cap_p, t_bias, l_stab, dtp);

  // 5. three leapfrog gradient evaluations
  const int   j0r[3]  = {0, 512, 0};     // W1 row block (q rows / p rows)
  const int   offs[3] = {512, 0, 512};   // which half of z to update
  const float coef[3] = {-0.5f, 1.0f, -0.5f};

  dim3 gridSq(16, 16, 1);   // 2048x2048, 128x128 tiles -> 256 blocks (1/CU)
  dim3 gridGr(4, 16, 4);    // 2048x512, split-K=4      -> 256 blocks

  for (int i = 0; i < 3; i++) {
    // h1 = tanh(z @ W1 + b1)                      (bf16 out)
    mfma_gemm<1><<<gridSq, thr512, 0, stream>>>(zb, ZD, W1t, ZD, h1b, ZD, b1,
                                                nullptr, 0, ZD);
    // g2 = (1 - tanh(h1 @ W2 + b2)^2) * W3[col]   (bf16 out)
    mfma_gemm<2><<<gridSq, thr512, 0, stream>>>(h1b, ZD, W2t, ZD, g2b, ZD, b2,
                                                W3, 0, ZD);
    // g1 = (g2 @ W2^T) * (1 - h1^2)               (bf16 out)
    mfma_gemm<3><<<gridSq, thr512, 0, stream>>>(g2b, ZD, W2n, ZD, g1b, ZD,
                                                nullptr, h1b, ZD, ZD);
    // gpart[z] = g1 @ W1[j0 : j0+512, :]^T  (f32 partials, split-K=4)
    mfma_gemm<0><<<gridGr, thr512, 0, stream>>>(
        g1b, ZD, W1n + (size_t)j0r[i] * ZD, ZD, gpart, SD, nullptr, nullptr, 0,
        SD);
    // z[:, offs] += coef * dt * sum(gpart)
    update_kernel<<<dim3(NB * SD / 4 / 256), thr256, 0, stream>>>(
        z, zb, gpart, dtp, coef[i], offs[i]);
  }

  // 6. out = z[:, :1024] @ W_out + b_out  (split-K=2 partials, then reduce)
  mfma_gemm<0><<<dim3(8, 16, 2), thr512, 0, stream>>>(
      zb, ZD, Wot, 1024, gpart, 1024, nullptr, nullptr, 0, 512);
  wout_reduce<<<dim3(NB * 1024 / 4 / 256), thr256, 0, stream>>>(gpart, b_out,
                                                                out_mat);

  // 7. h_next writeback
  hnext_kernel<<<dim3(NELEM_Z / 4 / 256), thr256, 0, stream>>>(z, out_hnxt);
}

// Round 5
// 588.444 us; speedup vs baseline: 6.3085x; 1.0598x over previous
//
#include <hip/hip_runtime.h>
#include <math.h>

// Problem constants
#define NB 2048            // batch
#define ZD 2048            // z dim = 2*512 + 1024, also D_H
#define SD 512             // state dim
#define NELEM_Z (NB * ZD)  // 4194304
#define MB_ (1024 * 1024)

typedef float f32x4 __attribute__((ext_vector_type(4)));
typedef __bf16 bf16x8 __attribute__((ext_vector_type(8)));
typedef __bf16 bf16x4 __attribute__((ext_vector_type(4)));

__device__ __forceinline__ float softplus_f(float x) {
  if (x > 20.f) return x;
  if (x < -20.f) return expf(x);
  return log1pf(expf(x));
}

__device__ __forceinline__ void gload_lds16(const __bf16* g, __bf16* l) {
  __builtin_amdgcn_global_load_lds(
      (__attribute__((address_space(1))) void*)(g),
      (__attribute__((address_space(3))) void*)(l), 16, 0, 0);
}

// ---------------------------------------------------------------------------
// Build z = [q, p, x] (B x 2048) f32 + bf16 mirror; zero accumulator. x4 vec.
// ---------------------------------------------------------------------------
__global__ void build_z_kernel(const float* __restrict__ x,
                               const float* __restrict__ h_padded,
                               float* __restrict__ z,
                               __bf16* __restrict__ zb,
                               float* __restrict__ acc) {
  int t = blockIdx.x * blockDim.x + threadIdx.x;  // 0 .. NELEM_Z/4
  if (t == 0) acc[0] = 0.f;
  int b = t >> 9;          // 512 f32x4 per row
  int i4 = t & 511;
  f32x4 v = (i4 < 256) ? ((const f32x4*)h_padded)[t]
                       : ((const f32x4*)x)[b * 256 + (i4 - 256)];
  ((f32x4*)z)[t] = v;
  bf16x4 o;
  o[0] = (__bf16)v[0]; o[1] = (__bf16)v[1];
  o[2] = (__bf16)v[2]; o[3] = (__bf16)v[3];
  ((bf16x4*)zb)[t] = o;
}

// ---------------------------------------------------------------------------
// Weight prep: in f32 (R x C) -> outN bf16 (R x C, optional) and outT bf16
// (C x R, transposed). block (32,8), grid (C/32, R/32)
// ---------------------------------------------------------------------------
__global__ void prep_w(const float* __restrict__ in,
                       __bf16* __restrict__ outN,
                       __bf16* __restrict__ outT, int R, int C) {
  __shared__ float tile[32][33];
  int bx = blockIdx.x * 32, by = blockIdx.y * 32;
  int tx = threadIdx.x, ty = threadIdx.y;
  for (int r = ty; r < 32; r += 8) {
    float v = in[(size_t)(by + r) * C + bx + tx];
    tile[r][tx] = v;
    if (outN) outN[(size_t)(by + r) * C + bx + tx] = (__bf16)v;
  }
  __syncthreads();
  for (int r = ty; r < 32; r += 8)
    outT[(size_t)(bx + r) * R + by + tx] = (__bf16)tile[tx][r];
}

// ---------------------------------------------------------------------------
// VQC: one 256-thread block (4 waves) per batch row.
// ---------------------------------------------------------------------------
__global__ __launch_bounds__(256) void vqc_kernel(
    const float* __restrict__ z,
    const float* __restrict__ enc_W,  // (2048,6)
    const float* __restrict__ enc_b,  // (6,)
    const float* __restrict__ thetas, // (3,6)
    const float* __restrict__ gain,
    const float* __restrict__ shift,
    float* __restrict__ acc) {
  int b = blockIdx.x;
  int lane = threadIdx.x & 63;
  int w = threadIdx.x >> 6;  // 0..3
  const float* zrow = z + (size_t)b * ZD;
  __shared__ float red[4][6];

  float pa[6] = {0.f, 0.f, 0.f, 0.f, 0.f, 0.f};
  int j0 = w * 512;
#pragma unroll
  for (int t = 0; t < 8; t++) {
    int j = j0 + t * 64 + lane;
    float c = (j < 1024) ? zrow[1024 + j] : zrow[j - 1024];
    const float* wp = enc_W + j * 6;
#pragma unroll
    for (int k = 0; k < 6; k++) pa[k] += c * wp[k];
  }
#pragma unroll
  for (int k = 0; k < 6; k++)
    for (int off = 32; off > 0; off >>= 1) pa[k] += __shfl_down(pa[k], off, 64);
  if (lane == 0) {
#pragma unroll
    for (int k = 0; k < 6; k++) red[w][k] = pa[k];
  }
  __syncthreads();

  if (w == 0) {
    float ang[6];
#pragma unroll
    for (int k = 0; k < 6; k++)
      ang[k] = red[0][k] + red[1][k] + red[2][k] + red[3][k] + enc_b[k];

    float s = (lane == 0) ? 1.f : 0.f;
    int rot = ((lane << 1) | (lane >> 5)) & 63;
    float cz = (__popc(lane & rot) & 1) ? -1.f : 1.f;

#pragma unroll
    for (int k = 0; k < 6; k++) {
      float half = 0.5f * ang[k];
      float c = cosf(half), si = sinf(half);
      int m = 1 << (5 - k);
      float other = __shfl_xor(s, m, 64);
      s = (lane & m) ? (si * other + c * s) : (c * s - si * other);
    }
    for (int l = 0; l < 3; l++) {
#pragma unroll
      for (int k = 0; k < 6; k++) {
        float half = 0.5f * thetas[l * 6 + k];
        float c = cosf(half), si = sinf(half);
        int m = 1 << (5 - k);
        float other = __shfl_xor(s, m, 64);
        s = (lane & m) ? (si * other + c * s) : (c * s - si * other);
      }
      s *= cz;
    }

    float zobs = (6.f - 2.f * (float)__popc(lane)) * (1.f / 6.f);
    float val = s * s * zobs;
    for (int off = 32; off > 0; off >>= 1) val += __shfl_down(val, off, 64);

    if (lane == 0) {
      float sg = softplus_f(gain[0]);
      float ss = softplus_f(shift[0]);
      atomicAdd(acc, softplus_f(sg * val - ss));
    }
  }
}

// ---------------------------------------------------------------------------
// dt scalar chain
// ---------------------------------------------------------------------------
__global__ void dt_kernel(const float* __restrict__ acc,
                          const float* __restrict__ cap_param,
                          const float* __restrict__ time_bias,
                          const float* __restrict__ last_stable,
                          float* __restrict__ dt_out) {
  float raw = acc[0] * (1.f / (float)NB) + time_bias[0];
  float cap = fmaxf(softplus_f(cap_param[0]), 1e-6f);
  float evo = cap / (1.f + expf(-raw / cap));
  if (!isfinite(evo)) evo = cap / (1.f + expf(-time_bias[0] / cap));
  float prev = fmaxf(last_stable[0], 1e-6f);
  float cand = fmaxf(evo, 1e-6f);
  float max_step = fmaxf(prev * 0.1f, 1e-4f);
  cand = fminf(cand, prev + max_step);
  cand = fminf(cand, 0.05f);
  dt_out[0] = isfinite(cand) ? cand : prev;
}

// ---------------------------------------------------------------------------
// MFMA bf16 GEMM, split-K partials: P[z][M,N] = A[M, koff:koff+Ks] @ Bt^T
// Block tile 128x128, 256 thr = 4 waves in 2x2, wave-tile 64x64
// (4x4 of 16x16x32 MFMA, acc 64 VGPR). BK=64, double-buffered LDS (64 KiB ->
// exactly 2 blocks/CU; grid z-dim provides the 2nd co-resident block so the
// two barrier groups overlap each other's vmcnt drains).
// LDS chunk swizzle: storage chunk c = m*8+cc holds k-octet o = cc ^ (m&7)
//  -> 128B-coalesced staging, tid-linear LDS dests (gload_lds rule), and
//  exactly 2-way (free) ds_read_b128 fragment reads.
// ---------------------------------------------------------------------------
__global__ __launch_bounds__(256, 2) void mfma_gemm(
    const __bf16* __restrict__ A, int lda,
    const __bf16* __restrict__ Bt, int ldb,
    float* __restrict__ P, int ldc,
    int Kslice) {
  __shared__ __bf16 sA[2][128 * 64];
  __shared__ __bf16 sB[2][128 * 64];

  const int tid = threadIdx.x;
  const int lane = tid & 63;
  const int w = tid >> 6;            // 0..3
  const int wm = w & 1, wn = w >> 1; // 2x2 wave grid, wave-tile 64x64
  const int row0 = blockIdx.y * 128;
  const int col0 = blockIdx.x * 128;
  const int koff = blockIdx.z * Kslice;

  // --- staging: 4 A-chunks + 4 B-chunks per thread per tile ---
  const __bf16* gA[4]; const __bf16* gB[4]; int lof[4];
#pragma unroll
  for (int i = 0; i < 4; i++) {
    int c = i * 256 + tid;
    int m = c >> 3, cc = c & 7;
    int o = cc ^ (m & 7);
    gA[i] = A + (size_t)(row0 + m) * lda + koff + o * 8;
    gB[i] = Bt + (size_t)(col0 + m) * ldb + koff + o * 8;
    lof[i] = c * 8;
  }

  // --- fragment LDS offsets (k0-invariant) ---
  const int q = lane >> 4, r = lane & 15;
  int aoff[4][2], boff[4][2];
#pragma unroll
  for (int i = 0; i < 4; i++) {
    int ma = wm * 64 + i * 16 + r;
    int mb = wn * 64 + i * 16 + r;
#pragma unroll
    for (int h = 0; h < 2; h++) {
      aoff[i][h] = (ma * 8 + ((h * 4 + q) ^ (ma & 7))) * 8;
      boff[i][h] = (mb * 8 + ((h * 4 + q) ^ (mb & 7))) * 8;
    }
  }

  f32x4 acc[4][4] = {};

  // prefetch tile 0 into buf 0
#pragma unroll
  for (int i = 0; i < 4; i++) gload_lds16(gA[i], &sA[0][0] + lof[i]);
#pragma unroll
  for (int i = 0; i < 4; i++) gload_lds16(gB[i], &sB[0][0] + lof[i]);

  int cur = 0;
  for (int k0 = 0; k0 < Kslice; k0 += 64) {
    __syncthreads();  // tile-k landed (vmcnt drain); prev-iter LDS reads done

    if (k0 + 64 < Kslice) {  // stage tile k+1 into other buffer
      int nxt = cur ^ 1;
#pragma unroll
      for (int i = 0; i < 4; i++)
        gload_lds16(gA[i] + k0 + 64, &sA[nxt][0] + lof[i]);
#pragma unroll
      for (int i = 0; i < 4; i++)
        gload_lds16(gB[i] + k0 + 64, &sB[nxt][0] + lof[i]);
    }

#pragma unroll
    for (int h = 0; h < 2; h++) {
      bf16x8 af[4], bfr[4];
#pragma unroll
      for (int i = 0; i < 4; i++)
        af[i] = *(const bf16x8*)(&sA[cur][0] + aoff[i][h]);
#pragma unroll
      for (int j = 0; j < 4; j++)
        bfr[j] = *(const bf16x8*)(&sB[cur][0] + boff[j][h]);
#pragma unroll
      for (int i = 0; i < 4; i++)
#pragma unroll
        for (int j = 0; j < 4; j++)
          acc[i][j] = __builtin_amdgcn_mfma_f32_16x16x32_bf16(af[i], bfr[j],
                                                              acc[i][j], 0, 0, 0);
    }
    cur ^= 1;
  }

  // --- epilogue: f32 partial. C/D layout col=lane&15, row=(lane>>4)*4+reg ---
  float* Pz = P + (size_t)blockIdx.z * (size_t)gridDim.y * 128 * ldc;
#pragma unroll
  for (int i = 0; i < 4; i++) {
    int rowb = row0 + wm * 64 + i * 16 + q * 4;
#pragma unroll
    for (int j = 0; j < 4; j++) {
      int col = col0 + wn * 64 + j * 16 + r;
#pragma unroll
      for (int g = 0; g < 4; g++)
        Pz[(size_t)(rowb + g) * ldc + col] = acc[i][j][g];
    }
  }
}

// ---------------------------------------------------------------------------
// Split-K=2 reduce + epilogue over (NB x ZD), f32x4 vectorized.
// MODE 1: out = tanh(p0+p1 + b[col])                      (h1, bf16)
// MODE 2: t = tanh(p0+p1 + b[col]); out = (1-t^2)*w3[col] (g2, bf16)
// MODE 3: out = (p0+p1) * (1 - h^2), h = aux[same idx]    (g1, bf16)
// ---------------------------------------------------------------------------
template <int MODE>
__global__ void red_epi(const float* __restrict__ P,
                        const float* __restrict__ bias,
                        const float* __restrict__ w3,
                        const __bf16* __restrict__ aux,
                        __bf16* __restrict__ out) {
  int t = blockIdx.x * blockDim.x + threadIdx.x;  // 0 .. NB*ZD/4
  constexpr int S = NB * ZD / 4;
  int col4 = t & 511;  // ZD/4 = 512
  const f32x4* p4 = (const f32x4*)P;
  f32x4 v = p4[t] + p4[t + S];
  bf16x4 o;
  if (MODE == 1) {
    f32x4 bb = ((const f32x4*)bias)[col4];
#pragma unroll
    for (int j = 0; j < 4; j++) o[j] = (__bf16)tanhf(v[j] + bb[j]);
  } else if (MODE == 2) {
    f32x4 bb = ((const f32x4*)bias)[col4];
    f32x4 ww = ((const f32x4*)w3)[col4];
#pragma unroll
    for (int j = 0; j < 4; j++) {
      float tt = tanhf(v[j] + bb[j]);
      o[j] = (__bf16)((1.f - tt * tt) * ww[j]);
    }
  } else {
    bf16x4 hh = ((const bf16x4*)aux)[t];
#pragma unroll
    for (int j = 0; j < 4; j++) {
      float h = (float)hh[j];
      o[j] = (__bf16)(v[j] * (1.f - h * h));
    }
  }
  ((bf16x4*)out)[t] = o;
}

// ---------------------------------------------------------------------------
// grad = sum of 8 split-K partials; z[:, off:off+512] += coef*dt*grad (x4 vec)
// ---------------------------------------------------------------------------
__global__ void update_kernel(float* __restrict__ z, __bf16* __restrict__ zb,
                              const float* __restrict__ gp,
                              const float* __restrict__ dt,
                              float coef, int off) {
  int t = blockIdx.x * blockDim.x + threadIdx.x;  // 0 .. NB*SD/4
  int b = t >> 7;  // 128 f32x4 per row
  int j4 = t & 127;
  const f32x4* g4 = (const f32x4*)gp;
  constexpr int STRIDE = NB * SD / 4;
  f32x4 g = g4[t];
#pragma unroll
  for (int zi = 1; zi < 8; zi++) g += g4[t + zi * STRIDE];
  int zi4 = (b * ZD + off) / 4 + j4;
  f32x4 v = ((f32x4*)z)[zi4];
  float s = coef * dt[0];
  v[0] += s * g[0]; v[1] += s * g[1]; v[2] += s * g[2]; v[3] += s * g[3];
  ((f32x4*)z)[zi4] = v;
  bf16x4 o;
  o[0] = (__bf16)v[0]; o[1] = (__bf16)v[1];
  o[2] = (__bf16)v[2]; o[3] = (__bf16)v[3];
  ((bf16x4*)zb)[zi4] = o;
}

// ---------------------------------------------------------------------------
// W_out split-K=4 reduce + bias: out[b,c] = sum(p) + b_out[c]  (f32, x4 vec)
// ---------------------------------------------------------------------------
__global__ void wout_reduce(const float* __restrict__ gp,
                            const float* __restrict__ b_out,
                            float* __restrict__ out) {
  int t = blockIdx.x * blockDim.x + threadIdx.x;  // 0 .. NB*1024/4
  constexpr int S = NB * 1024 / 4;
  const f32x4* g4 = (const f32x4*)gp;
  f32x4 v = g4[t] + g4[t + S] + g4[t + 2 * S] + g4[t + 3 * S];
  f32x4 bb = ((const f32x4*)b_out)[t & 255];
  v[0] += bb[0]; v[1] += bb[1]; v[2] += bb[2]; v[3] += bb[3];
  ((f32x4*)out)[t] = v;
}

// ---------------------------------------------------------------------------
// h_next: first 8 slices = z[:, :1024] (exact f32), rest zero (x4 vec)
// ---------------------------------------------------------------------------
__global__ void hnext_kernel(const float* __restrict__ z,
                             float* __restrict__ out) {
  int t = blockIdx.x * blockDim.x + threadIdx.x;  // 0 .. NELEM_Z/4
  int i4 = t & 511;
  f32x4 zero = {0.f, 0.f, 0.f, 0.f};
  ((f32x4*)out)[t] = (i4 < 256) ? ((const f32x4*)z)[t] : zero;
}

// ---------------------------------------------------------------------------
extern "C" void kernel_launch(void* const* d_in, const int* in_sizes, int n_in,
                              void* d_out, int out_size, void* d_ws,
                              size_t ws_size, hipStream_t stream) {
  const float* x        = (const float*)d_in[0];
  const float* h_padded = (const float*)d_in[1];
  const float* W1    = (const float*)d_in[3];
  const float* b1    = (const float*)d_in[4];
  const float* W2    = (const float*)d_in[5];
  const float* b2    = (const float*)d_in[6];
  const float* W3    = (const float*)d_in[7];
  const float* W_out = (const float*)d_in[9];
  const float* b_out = (const float*)d_in[10];
  const float* enc_W = (const float*)d_in[11];
  const float* enc_b = (const float*)d_in[12];
  const float* thetas = (const float*)d_in[13];
  const float* gain   = (const float*)d_in[14];
  const float* shift  = (const float*)d_in[15];
  const float* cap_p  = (const float*)d_in[16];
  const float* t_bias = (const float*)d_in[17];
  const float* l_stab = (const float*)d_in[18];

  float* out_mat  = (float*)d_out;              // (2048,1024)
  float* out_hnxt = (float*)d_out + NB * 1024;  // (2048,16,128)

  // workspace layout
  char* base = (char*)d_ws;
  float* z      = (float*)(base);                     // 16MB
  float* part   = (float*)(base + 16 * MB_);          // 32MB split-K partials
  float* accp   = (float*)(base + 48 * MB_);          // scalars
  float* dtp    = accp + 1;
  __bf16* zb    = (__bf16*)(base + 48 * MB_ + 1024);  // 8MB
  __bf16* h1b   = zb + (size_t)NELEM_Z;               // 8MB
  __bf16* g2b   = h1b + (size_t)NELEM_Z;              // 8MB
  __bf16* g1b   = g2b + (size_t)NELEM_Z;              // 8MB
  __bf16* W1n   = g1b + (size_t)NELEM_Z;              // 8MB
  __bf16* W1t   = W1n + (size_t)NELEM_Z;              // 8MB
  __bf16* W2n   = W1t + (size_t)NELEM_Z;              // 8MB
  __bf16* W2t   = W2n + (size_t)NELEM_Z;              // 8MB
  __bf16* Wot   = W2t + (size_t)NELEM_Z;              // 2MB

  dim3 thr256(256);
  dim3 thrT(32, 8);

  // 1. weight prep (convert + transpose fused)
  prep_w<<<dim3(64, 64), thrT, 0, stream>>>(W1, W1n, W1t, ZD, ZD);
  prep_w<<<dim3(64, 64), thrT, 0, stream>>>(W2, W2n, W2t, ZD, ZD);
  prep_w<<<dim3(32, 32), thrT, 0, stream>>>(W_out, nullptr, Wot, 1024, 1024);

  // 2. build z (f32 + bf16) + zero acc
  build_z_kernel<<<dim3(NELEM_Z / 4 / 256), thr256, 0, stream>>>(x, h_padded, z,
                                                                 zb, accp);
  // 3. VQC -> acc ; 4. dt
  vqc_kernel<<<dim3(NB), thr256, 0, stream>>>(z, enc_W, enc_b, thetas, gain,
                                              shift, accp);
  dt_kernel<<<dim3(1), dim3(1), 0, stream>>>(accp, cap_p, t_bias, l_stab, dtp);

  // 5. three leapfrog gradient evaluations
  const int   j0r[3]  = {0, 512, 0};     // W1 row block (q rows / p rows)
  const int   offs[3] = {512, 0, 512};   // which half of z to update
  const float coef[3] = {-0.5f, 1.0f, -0.5f};

  dim3 gridSq(16, 16, 2);   // 2048x2048, split-K=2 -> 512 blocks (2/CU)
  dim3 gridGr(4, 16, 8);    // 2048x512,  split-K=8 -> 512 blocks
  dim3 gridRed(NELEM_Z / 4 / 256);

  for (int i = 0; i < 3; i++) {
    // h1 = tanh(z @ W1 + b1)
    mfma_gemm<<<gridSq, thr256, 0, stream>>>(zb, ZD, W1t, ZD, part, ZD, 1024);
    red_epi<1><<<gridRed, thr256, 0, stream>>>(part, b1, nullptr, nullptr, h1b);
    // g2 = (1 - tanh(h1 @ W2 + b2)^2) * W3[col]
    mfma_gemm<<<gridSq, thr256, 0, stream>>>(h1b, ZD, W2t, ZD, part, ZD, 1024);
    red_epi<2><<<gridRed, thr256, 0, stream>>>(part, b2, W3, nullptr, g2b);
    // g1 = (g2 @ W2^T) * (1 - h1^2)
    mfma_gemm<<<gridSq, thr256, 0, stream>>>(g2b, ZD, W2n, ZD, part, ZD, 1024);
    red_epi<3><<<gridRed, thr256, 0, stream>>>(part, nullptr, nullptr, h1b, g1b);
    // gpart = g1 @ W1[j0 : j0+512, :]^T  (f32 partials, split-K=8)
    mfma_gemm<<<gridGr, thr256, 0, stream>>>(g1b, ZD,
                                             W1n + (size_t)j0r[i] * ZD, ZD,
                                             part, SD, 256);
    // z[:, offs] += coef * dt * sum(gpart)
    update_kernel<<<dim3(NB * SD / 4 / 256), thr256, 0, stream>>>(
        z, zb, part, dtp, coef[i], offs[i]);
  }

  // 6. out = z[:, :1024] @ W_out + b_out  (split-K=4 partials, then reduce)
  mfma_gemm<<<dim3(8, 16, 4), thr256, 0, stream>>>(zb, ZD, Wot, 1024, part,
                                                   1024, 256);
  wout_reduce<<<dim3(NB * 1024 / 4 / 256), thr256, 0, stream>>>(part, b_out,
                                                                out_mat);

  // 7. h_next writeback
  hnext_kernel<<<dim3(NELEM_Z / 4 / 256), thr256, 0, stream>>>(z, out_hnxt);
}

// Round 6
// 559.958 us; speedup vs baseline: 6.6294x; 1.0509x over previous
//
#include <hip/hip_runtime.h>
#include <math.h>

// Problem constants
#define NB 2048            // batch
#define ZD 2048            // z dim = 2*512 + 1024, also D_H
#define SD 512             // state dim
#define NELEM_Z (NB * ZD)  // 4194304
#define MB_ (1024 * 1024)

typedef float f32x4 __attribute__((ext_vector_type(4)));
typedef __bf16 bf16x8 __attribute__((ext_vector_type(8)));
typedef __bf16 bf16x4 __attribute__((ext_vector_type(4)));

__device__ __forceinline__ float softplus_f(float x) {
  if (x > 20.f) return x;
  if (x < -20.f) return expf(x);
  return log1pf(expf(x));
}

__device__ __forceinline__ void gload_lds16(const __bf16* g, __bf16* l) {
  __builtin_amdgcn_global_load_lds(
      (__attribute__((address_space(1))) void*)(g),
      (__attribute__((address_space(3))) void*)(l), 16, 0, 0);
}

// ---------------------------------------------------------------------------
// Build z = [q, p, x] (B x 2048) f32 + bf16 mirror; zero accumulator. x4 vec.
// ---------------------------------------------------------------------------
__global__ void build_z_kernel(const float* __restrict__ x,
                               const float* __restrict__ h_padded,
                               float* __restrict__ z,
                               __bf16* __restrict__ zb,
                               float* __restrict__ acc) {
  int t = blockIdx.x * blockDim.x + threadIdx.x;  // 0 .. NELEM_Z/4
  if (t == 0) acc[0] = 0.f;
  int b = t >> 9;          // 512 f32x4 per row
  int i4 = t & 511;
  f32x4 v = (i4 < 256) ? ((const f32x4*)h_padded)[t]
                       : ((const f32x4*)x)[b * 256 + (i4 - 256)];
  ((f32x4*)z)[t] = v;
  bf16x4 o;
  o[0] = (__bf16)v[0]; o[1] = (__bf16)v[1];
  o[2] = (__bf16)v[2]; o[3] = (__bf16)v[3];
  ((bf16x4*)zb)[t] = o;
}

// ---------------------------------------------------------------------------
// Weight prep: in f32 (R x C) -> outN bf16 (R x C, optional) and outT bf16
// (C x R, transposed). block (32,8), grid (C/32, R/32)
// ---------------------------------------------------------------------------
__global__ void prep_w(const float* __restrict__ in,
                       __bf16* __restrict__ outN,
                       __bf16* __restrict__ outT, int R, int C) {
  __shared__ float tile[32][33];
  int bx = blockIdx.x * 32, by = blockIdx.y * 32;
  int tx = threadIdx.x, ty = threadIdx.y;
  for (int r = ty; r < 32; r += 8) {
    float v = in[(size_t)(by + r) * C + bx + tx];
    tile[r][tx] = v;
    if (outN) outN[(size_t)(by + r) * C + bx + tx] = (__bf16)v;
  }
  __syncthreads();
  for (int r = ty; r < 32; r += 8)
    outT[(size_t)(bx + r) * R + by + tx] = (__bf16)tile[tx][r];
}

// ---------------------------------------------------------------------------
// Angles: wave-per-row dot product. angles[row][k] = ctrl(row) . enc_W[:,k] + b
// ctrl[j] = (j<1024) ? z[row][1024+j] : z[row][j-1024].  grid 512 x 256thr.
// ---------------------------------------------------------------------------
__global__ __launch_bounds__(256) void angles_kernel(
    const float* __restrict__ z,
    const float* __restrict__ enc_W,  // (2048,6)
    const float* __restrict__ enc_b,  // (6,)
    float* __restrict__ angles) {     // (2048,6)
  int w = threadIdx.x >> 6, lane = threadIdx.x & 63;
  int row = blockIdx.x * 4 + w;
  const float* zrow = z + (size_t)row * ZD;
  float pa[6] = {0.f, 0.f, 0.f, 0.f, 0.f, 0.f};
#pragma unroll
  for (int t = 0; t < 32; t++) {
    int j = t * 64 + lane;
    float c = (j < 1024) ? zrow[1024 + j] : zrow[j - 1024];
    const float* wp = enc_W + j * 6;
#pragma unroll
    for (int k = 0; k < 6; k++) pa[k] += c * wp[k];
  }
#pragma unroll
  for (int k = 0; k < 6; k++)
    for (int off = 32; off > 0; off >>= 1) pa[k] += __shfl_down(pa[k], off, 64);
  if (lane == 0) {
#pragma unroll
    for (int k = 0; k < 6; k++) angles[row * 6 + k] = pa[k] + enc_b[k];
  }
}

// ---------------------------------------------------------------------------
// Statevector sim: ONE BATCH ROW PER LANE. 64 amplitudes in 64 registers;
// each RY gate = 32 in-register pair rotations (compile-time indices, no
// shuffles, no LDS). 2048 rows = 2048 fully independent lanes.
// ---------------------------------------------------------------------------
__global__ __launch_bounds__(64) void sim_kernel(
    const float* __restrict__ angles,  // (2048,6)
    const float* __restrict__ thetas,  // (3,6)
    const float* __restrict__ gain,
    const float* __restrict__ shift,
    float* __restrict__ acc) {
  int row = blockIdx.x * 64 + threadIdx.x;
  const float* a = angles + row * 6;

  float s[64];
#pragma unroll
  for (int i = 0; i < 64; i++) s[i] = 0.f;
  s[0] = 1.f;

  // encoding RY layer (per-row angles)
#pragma unroll
  for (int k = 0; k < 6; k++) {
    float half = 0.5f * a[k];
    float c = cosf(half), si = sinf(half);
    int m = 1 << (5 - k);
#pragma unroll
    for (int i = 0; i < 64; i++) {
      if ((i & m) == 0) {
        float a0 = s[i], a1 = s[i | m];
        s[i] = c * a0 - si * a1;
        s[i | m] = si * a0 + c * a1;
      }
    }
  }
  // 3 variational layers (uniform thetas) + CZ ring sign
#pragma unroll
  for (int l = 0; l < 3; l++) {
#pragma unroll
    for (int k = 0; k < 6; k++) {
      float half = 0.5f * thetas[l * 6 + k];
      float c = cosf(half), si = sinf(half);
      int m = 1 << (5 - k);
#pragma unroll
      for (int i = 0; i < 64; i++) {
        if ((i & m) == 0) {
          float a0 = s[i], a1 = s[i | m];
          s[i] = c * a0 - si * a1;
          s[i | m] = si * a0 + c * a1;
        }
      }
    }
#pragma unroll
    for (int i = 0; i < 64; i++) {
      int rot = ((i << 1) | (i >> 5)) & 63;
      if (__popc(i & rot) & 1) s[i] = -s[i];
    }
  }

  float val = 0.f;
#pragma unroll
  for (int i = 0; i < 64; i++) {
    float zo = (6.f - 2.f * (float)__popc(i)) * (1.f / 6.f);
    val += s[i] * s[i] * zo;
  }
  float sg = softplus_f(gain[0]);
  float ss = softplus_f(shift[0]);
  float adj = softplus_f(sg * val - ss);
  for (int off = 32; off > 0; off >>= 1) adj += __shfl_down(adj, off, 64);
  if (threadIdx.x == 0) atomicAdd(acc, adj);
}

// ---------------------------------------------------------------------------
// dt scalar chain
// ---------------------------------------------------------------------------
__global__ void dt_kernel(const float* __restrict__ acc,
                          const float* __restrict__ cap_param,
                          const float* __restrict__ time_bias,
                          const float* __restrict__ last_stable,
                          float* __restrict__ dt_out) {
  float raw = acc[0] * (1.f / (float)NB) + time_bias[0];
  float cap = fmaxf(softplus_f(cap_param[0]), 1e-6f);
  float evo = cap / (1.f + expf(-raw / cap));
  if (!isfinite(evo)) evo = cap / (1.f + expf(-time_bias[0] / cap));
  float prev = fmaxf(last_stable[0], 1e-6f);
  float cand = fmaxf(evo, 1e-6f);
  float max_step = fmaxf(prev * 0.1f, 1e-4f);
  cand = fminf(cand, prev + max_step);
  cand = fminf(cand, 0.05f);
  dt_out[0] = isfinite(cand) ? cand : prev;
}

// ---------------------------------------------------------------------------
// MFMA bf16 GEMM, fused epilogue: C[M,N] = epi( A[M,K] @ Bt[N,K]^T )
// Block tile 128x64, 256 thr = 4 waves (wave-tile 64 rows x 32 cols,
// 4x2 of 16x16x32 MFMA). BK=64 double-buffered LDS (48 KiB -> grid 512 gives
// 2 co-resident blocks/CU = 2 independent barrier groups overlapping their
// vmcnt drains; 8 waves/CU).
// LDS chunk swizzle: storage chunk c = m*8+cc holds k-octet o = cc ^ (m&7)
//  -> 128B-coalesced staging, tid-linear LDS dests, 2-way (free) ds_read_b128.
// EPI: 0 f32 split-K partial | 1 bf16 tanh(v+bias[col])
//      2 bf16 (1-t^2)*auxf[col] | 3 bf16 v*(1-h^2), h=auxb[row,col]
// ---------------------------------------------------------------------------
template <int EPI>
__global__ __launch_bounds__(256, 2) void mfma_gemm(
    const __bf16* __restrict__ A, int lda,
    const __bf16* __restrict__ Bt, int ldb,
    void* __restrict__ Cv, int ldc,
    const float* __restrict__ bias,
    const void* __restrict__ aux, int ldaux,
    int Kslice) {
  __shared__ __bf16 sA[2][128 * 64];
  __shared__ __bf16 sB[2][64 * 64];

  const int tid = threadIdx.x;
  const int lane = tid & 63;
  const int w = tid >> 6;            // 0..3
  const int wm = w & 1, wn = w >> 1; // wave-tile: rows wm*64+, cols wn*32+
  const int row0 = blockIdx.y * 128;
  const int col0 = blockIdx.x * 64;
  const int koff = blockIdx.z * Kslice;

  // --- staging: 4 A-chunks + 2 B-chunks per thread per tile ---
  const __bf16* gA[4]; int lofA[4];
  const __bf16* gB[2]; int lofB[2];
#pragma unroll
  for (int i = 0; i < 4; i++) {
    int c = i * 256 + tid;
    int m = c >> 3, cc = c & 7;
    int o = cc ^ (m & 7);
    gA[i] = A + (size_t)(row0 + m) * lda + koff + o * 8;
    lofA[i] = c * 8;
  }
#pragma unroll
  for (int i = 0; i < 2; i++) {
    int c = i * 256 + tid;
    int m = c >> 3, cc = c & 7;
    int o = cc ^ (m & 7);
    gB[i] = Bt + (size_t)(col0 + m) * ldb + koff + o * 8;
    lofB[i] = c * 8;
  }

  // --- fragment LDS offsets (k0-invariant) ---
  const int q = lane >> 4, r = lane & 15;
  int aoff[4][2], boff[2][2];
#pragma unroll
  for (int i = 0; i < 4; i++) {
    int ma = wm * 64 + i * 16 + r;
#pragma unroll
    for (int h = 0; h < 2; h++)
      aoff[i][h] = (ma * 8 + ((h * 4 + q) ^ (ma & 7))) * 8;
  }
#pragma unroll
  for (int j = 0; j < 2; j++) {
    int mb = wn * 32 + j * 16 + r;
#pragma unroll
    for (int h = 0; h < 2; h++)
      boff[j][h] = (mb * 8 + ((h * 4 + q) ^ (mb & 7))) * 8;
  }

  f32x4 acc[4][2] = {};

  // prefetch tile 0 into buf 0
#pragma unroll
  for (int i = 0; i < 4; i++) gload_lds16(gA[i], &sA[0][0] + lofA[i]);
#pragma unroll
  for (int i = 0; i < 2; i++) gload_lds16(gB[i], &sB[0][0] + lofB[i]);

  int cur = 0;
  for (int k0 = 0; k0 < Kslice; k0 += 64) {
    __syncthreads();  // tile-k landed (vmcnt drain); prev-iter LDS reads done

    if (k0 + 64 < Kslice) {  // stage tile k+1 into other buffer
      int nxt = cur ^ 1;
#pragma unroll
      for (int i = 0; i < 4; i++)
        gload_lds16(gA[i] + k0 + 64, &sA[nxt][0] + lofA[i]);
#pragma unroll
      for (int i = 0; i < 2; i++)
        gload_lds16(gB[i] + k0 + 64, &sB[nxt][0] + lofB[i]);
    }

#pragma unroll
    for (int h = 0; h < 2; h++) {
      bf16x8 af[4], bfr[2];
#pragma unroll
      for (int i = 0; i < 4; i++)
        af[i] = *(const bf16x8*)(&sA[cur][0] + aoff[i][h]);
#pragma unroll
      for (int j = 0; j < 2; j++)
        bfr[j] = *(const bf16x8*)(&sB[cur][0] + boff[j][h]);
#pragma unroll
      for (int i = 0; i < 4; i++)
#pragma unroll
        for (int j = 0; j < 2; j++)
          acc[i][j] = __builtin_amdgcn_mfma_f32_16x16x32_bf16(af[i], bfr[j],
                                                              acc[i][j], 0, 0, 0);
    }
    cur ^= 1;
  }

  // --- epilogue: C/D layout col=lane&15, row=(lane>>4)*4+reg ---
  float* Cf = (float*)Cv;
  __bf16* Cb = (__bf16*)Cv;
  const float* auxf = (const float*)aux;
  const __bf16* auxb = (const __bf16*)aux;
  float* Cz = Cf + (size_t)blockIdx.z * (size_t)gridDim.y * 128 * ldc;

#pragma unroll
  for (int i = 0; i < 4; i++) {
    int rowb = row0 + wm * 64 + i * 16 + q * 4;
#pragma unroll
    for (int j = 0; j < 2; j++) {
      int col = col0 + wn * 32 + j * 16 + r;
#pragma unroll
      for (int g = 0; g < 4; g++) {
        int row = rowb + g;
        size_t idx = (size_t)row * ldc + col;
        float v = acc[i][j][g];
        if (EPI == 0) {
          Cz[idx] = v;
        } else if (EPI == 1) {
          Cb[idx] = (__bf16)tanhf(v + bias[col]);
        } else if (EPI == 2) {
          float t = tanhf(v + bias[col]);
          Cb[idx] = (__bf16)((1.f - t * t) * auxf[col]);
        } else {
          float h = (float)auxb[(size_t)row * ldaux + col];
          Cb[idx] = (__bf16)(v * (1.f - h * h));
        }
      }
    }
  }
}

// ---------------------------------------------------------------------------
// grad = sum of 4 split-K partials; z[:, off:off+512] += coef*dt*grad (x4 vec)
// ---------------------------------------------------------------------------
__global__ void update_kernel(float* __restrict__ z, __bf16* __restrict__ zb,
                              const float* __restrict__ gp,
                              const float* __restrict__ dt,
                              float coef, int off) {
  int t = blockIdx.x * blockDim.x + threadIdx.x;  // 0 .. NB*SD/4
  int b = t >> 7;  // 128 f32x4 per row
  int j4 = t & 127;
  const f32x4* g4 = (const f32x4*)gp;
  constexpr int STRIDE = NB * SD / 4;
  f32x4 g = g4[t] + g4[t + STRIDE] + g4[t + 2 * STRIDE] + g4[t + 3 * STRIDE];
  int zi4 = (b * ZD + off) / 4 + j4;
  f32x4 v = ((f32x4*)z)[zi4];
  float s = coef * dt[0];
  v[0] += s * g[0]; v[1] += s * g[1]; v[2] += s * g[2]; v[3] += s * g[3];
  ((f32x4*)z)[zi4] = v;
  bf16x4 o;
  o[0] = (__bf16)v[0]; o[1] = (__bf16)v[1];
  o[2] = (__bf16)v[2]; o[3] = (__bf16)v[3];
  ((bf16x4*)zb)[zi4] = o;
}

// ---------------------------------------------------------------------------
// W_out split-K=2 reduce + bias: out[b,c] = p0 + p1 + b_out[c]  (f32, x4 vec)
// ---------------------------------------------------------------------------
__global__ void wout_reduce(const float* __restrict__ gp,
                            const float* __restrict__ b_out,
                            float* __restrict__ out) {
  int t = blockIdx.x * blockDim.x + threadIdx.x;  // 0 .. NB*1024/4
  constexpr int S = NB * 1024 / 4;
  const f32x4* g4 = (const f32x4*)gp;
  f32x4 v = g4[t] + g4[t + S];
  f32x4 bb = ((const f32x4*)b_out)[t & 255];
  v[0] += bb[0]; v[1] += bb[1]; v[2] += bb[2]; v[3] += bb[3];
  ((f32x4*)out)[t] = v;
}

// ---------------------------------------------------------------------------
// h_next: first 8 slices = z[:, :1024] (exact f32), rest zero (x4 vec)
// ---------------------------------------------------------------------------
__global__ void hnext_kernel(const float* __restrict__ z,
                             float* __restrict__ out) {
  int t = blockIdx.x * blockDim.x + threadIdx.x;  // 0 .. NELEM_Z/4
  int i4 = t & 511;
  f32x4 zero = {0.f, 0.f, 0.f, 0.f};
  ((f32x4*)out)[t] = (i4 < 256) ? ((const f32x4*)z)[t] : zero;
}

// ---------------------------------------------------------------------------
extern "C" void kernel_launch(void* const* d_in, const int* in_sizes, int n_in,
                              void* d_out, int out_size, void* d_ws,
                              size_t ws_size, hipStream_t stream) {
  const float* x        = (const float*)d_in[0];
  const float* h_padded = (const float*)d_in[1];
  const float* W1    = (const float*)d_in[3];
  const float* b1    = (const float*)d_in[4];
  const float* W2    = (const float*)d_in[5];
  const float* b2    = (const float*)d_in[6];
  const float* W3    = (const float*)d_in[7];
  const float* W_out = (const float*)d_in[9];
  const float* b_out = (const float*)d_in[10];
  const float* enc_W = (const float*)d_in[11];
  const float* enc_b = (const float*)d_in[12];
  const float* thetas = (const float*)d_in[13];
  const float* gain   = (const float*)d_in[14];
  const float* shift  = (const float*)d_in[15];
  const float* cap_p  = (const float*)d_in[16];
  const float* t_bias = (const float*)d_in[17];
  const float* l_stab = (const float*)d_in[18];

  float* out_mat  = (float*)d_out;              // (2048,1024)
  float* out_hnxt = (float*)d_out + NB * 1024;  // (2048,16,128)

  // workspace layout
  char* base = (char*)d_ws;
  float* z      = (float*)(base);                     // 16MB
  float* part   = (float*)(base + 16 * MB_);          // 16MB split-K partials
  float* angl   = (float*)(base + 32 * MB_);          // 48KB angles
  float* accp   = (float*)(base + 33 * MB_);          // scalars
  float* dtp    = accp + 1;
  __bf16* zb    = (__bf16*)(base + 33 * MB_ + 1024);  // 8MB
  __bf16* h1b   = zb + (size_t)NELEM_Z;               // 8MB
  __bf16* g2b   = h1b + (size_t)NELEM_Z;              // 8MB
  __bf16* g1b   = g2b + (size_t)NELEM_Z;              // 8MB
  __bf16* W1n   = g1b + (size_t)NELEM_Z;              // 8MB
  __bf16* W1t   = W1n + (size_t)NELEM_Z;              // 8MB
  __bf16* W2n   = W1t + (size_t)NELEM_Z;              // 8MB
  __bf16* W2t   = W2n + (size_t)NELEM_Z;              // 8MB
  __bf16* Wot   = W2t + (size_t)NELEM_Z;              // 2MB

  dim3 thr256(256);
  dim3 thrT(32, 8);

  // 1. weight prep (convert + transpose fused)
  prep_w<<<dim3(64, 64), thrT, 0, stream>>>(W1, W1n, W1t, ZD, ZD);
  prep_w<<<dim3(64, 64), thrT, 0, stream>>>(W2, W2n, W2t, ZD, ZD);
  prep_w<<<dim3(32, 32), thrT, 0, stream>>>(W_out, nullptr, Wot, 1024, 1024);

  // 2. build z (f32 + bf16) + zero acc
  build_z_kernel<<<dim3(NELEM_Z / 4 / 256), thr256, 0, stream>>>(x, h_padded, z,
                                                                 zb, accp);
  // 3. VQC: angles (wave/row) -> sim (row/lane) -> acc ; 4. dt
  angles_kernel<<<dim3(NB / 4), thr256, 0, stream>>>(z, enc_W, enc_b, angl);
  sim_kernel<<<dim3(NB / 64), dim3(64), 0, stream>>>(angl, thetas, gain, shift,
                                                     accp);
  dt_kernel<<<dim3(1), dim3(1), 0, stream>>>(accp, cap_p, t_bias, l_stab, dtp);

  // 5. three leapfrog gradient evaluations
  const int   j0r[3]  = {0, 512, 0};     // W1 row block (q rows / p rows)
  const int   offs[3] = {512, 0, 512};   // which half of z to update
  const float coef[3] = {-0.5f, 1.0f, -0.5f};

  dim3 gridSq(32, 16, 1);   // 2048x2048, 128x64 tiles -> 512 blocks (2/CU)
  dim3 gridGr(8, 16, 4);    // 2048x512, split-K=4     -> 512 blocks

  for (int i = 0; i < 3; i++) {
    // h1 = tanh(z @ W1 + b1)                      (bf16 out, fused)
    mfma_gemm<1><<<gridSq, thr256, 0, stream>>>(zb, ZD, W1t, ZD, h1b, ZD, b1,
                                                nullptr, 0, ZD);
    // g2 = (1 - tanh(h1 @ W2 + b2)^2) * W3[col]   (bf16 out, fused)
    mfma_gemm<2><<<gridSq, thr256, 0, stream>>>(h1b, ZD, W2t, ZD, g2b, ZD, b2,
                                                W3, 0, ZD);
    // g1 = (g2 @ W2^T) * (1 - h1^2)               (bf16 out, fused)
    mfma_gemm<3><<<gridSq, thr256, 0, stream>>>(g2b, ZD, W2n, ZD, g1b, ZD,
                                                nullptr, h1b, ZD, ZD);
    // part = g1 @ W1[j0 : j0+512, :]^T  (f32 partials, split-K=4)
    mfma_gemm<0><<<gridGr, thr256, 0, stream>>>(
        g1b, ZD, W1n + (size_t)j0r[i] * ZD, ZD, part, SD, nullptr, nullptr, 0,
        512);
    // z[:, offs] += coef * dt * sum(part)
    update_kernel<<<dim3(NB * SD / 4 / 256), thr256, 0, stream>>>(
        z, zb, part, dtp, coef[i], offs[i]);
  }

  // 6. out = z[:, :1024] @ W_out + b_out  (split-K=2 partials, then reduce)
  mfma_gemm<0><<<dim3(16, 16, 2), thr256, 0, stream>>>(
      zb, ZD, Wot, 1024, part, 1024, nullptr, nullptr, 0, 512);
  wout_reduce<<<dim3(NB * 1024 / 4 / 256), thr256, 0, stream>>>(part, b_out,
                                                                out_mat);

  // 7. h_next writeback
  hnext_kernel<<<dim3(NELEM_Z / 4 / 256), thr256, 0, stream>>>(z, out_hnxt);
}

// Round 7
// 481.449 us; speedup vs baseline: 7.7105x; 1.1631x over previous
//
#include <hip/hip_runtime.h>
#include <math.h>

// Problem constants
#define NB 2048            // batch
#define ZD 2048            // z dim = 2*512 + 1024, also D_H
#define SD 512             // state dim
#define NELEM_Z (NB * ZD)  // 4194304
#define MB_ (1024 * 1024)

typedef float f32x4 __attribute__((ext_vector_type(4)));
typedef __bf16 bf16x8 __attribute__((ext_vector_type(8)));
typedef __bf16 bf16x4 __attribute__((ext_vector_type(4)));

__device__ __forceinline__ float softplus_f(float x) {
  if (x > 20.f) return x;
  if (x < -20.f) return expf(x);
  return log1pf(expf(x));
}

__device__ __forceinline__ void gload_lds16(const __bf16* g, __bf16* l) {
  __builtin_amdgcn_global_load_lds(
      (__attribute__((address_space(1))) void*)(g),
      (__attribute__((address_space(3))) void*)(l), 16, 0, 0);
}

// pack 4 floats -> 4 fp8 e4m3 bytes (OCP on gfx950)
__device__ __forceinline__ int pack_fp8x4(float a, float b, float c, float d) {
  int p = __builtin_amdgcn_cvt_pk_fp8_f32(a, b, 0, false);
  p = __builtin_amdgcn_cvt_pk_fp8_f32(c, d, p, true);
  return p;
}
__device__ __forceinline__ float fp8_to_f32(unsigned char b) {
  return __builtin_amdgcn_cvt_f32_fp8((int)b, 0);
}

// ---------------------------------------------------------------------------
// Build z = [q, p, x] f32 + bf16 mirror (for W_out GEMM) + fp8 mirror (for
// grad-path GEMMs); zero accumulator. x4 vectorized.
// ---------------------------------------------------------------------------
__global__ void build_z_kernel(const float* __restrict__ x,
                               const float* __restrict__ h_padded,
                               float* __restrict__ z,
                               __bf16* __restrict__ zb,
                               unsigned char* __restrict__ zf8,
                               float* __restrict__ acc) {
  int t = blockIdx.x * blockDim.x + threadIdx.x;  // 0 .. NELEM_Z/4
  if (t == 0) acc[0] = 0.f;
  int b = t >> 9;          // 512 f32x4 per row
  int i4 = t & 511;
  f32x4 v = (i4 < 256) ? ((const f32x4*)h_padded)[t]
                       : ((const f32x4*)x)[b * 256 + (i4 - 256)];
  ((f32x4*)z)[t] = v;
  bf16x4 o;
  o[0] = (__bf16)v[0]; o[1] = (__bf16)v[1];
  o[2] = (__bf16)v[2]; o[3] = (__bf16)v[3];
  ((bf16x4*)zb)[t] = o;
  ((int*)zf8)[t] = pack_fp8x4(v[0], v[1], v[2], v[3]);
}

// ---------------------------------------------------------------------------
// bf16 weight prep (for W_out): f32 (R x C) -> transposed bf16 (C x R)
// ---------------------------------------------------------------------------
__global__ void prep_w(const float* __restrict__ in,
                       __bf16* __restrict__ outT, int R, int C) {
  __shared__ float tile[32][33];
  int bx = blockIdx.x * 32, by = blockIdx.y * 32;
  int tx = threadIdx.x, ty = threadIdx.y;
  for (int r = ty; r < 32; r += 8)
    tile[r][tx] = in[(size_t)(by + r) * C + bx + tx];
  __syncthreads();
  for (int r = ty; r < 32; r += 8)
    outT[(size_t)(bx + r) * R + by + tx] = (__bf16)tile[tx][r];
}

// ---------------------------------------------------------------------------
// fp8 weight prep: f32 (R x C) -> straight fp8 (R x C) and transposed fp8
// (C x R), both scaled by 16 (Glorot std ~0.026 sits at the e4m3 subnormal
// floor; x16 moves it into the normal range; epilogues divide by 16).
// ---------------------------------------------------------------------------
__global__ void prep_w8(const float* __restrict__ in,
                        unsigned char* __restrict__ outN,
                        unsigned char* __restrict__ outT, int R, int C) {
  __shared__ float tile[32][33];
  int bx = blockIdx.x * 32, by = blockIdx.y * 32;
  int tx = threadIdx.x, ty = threadIdx.y;
  for (int r = ty; r < 32; r += 8) {
    float v = in[(size_t)(by + r) * C + bx + tx] * 16.f;
    tile[r][tx] = v;
    int p = __builtin_amdgcn_cvt_pk_fp8_f32(v, v, 0, false);
    outN[(size_t)(by + r) * C + bx + tx] = (unsigned char)(p & 0xff);
  }
  __syncthreads();
  for (int r = ty; r < 32; r += 8) {
    float v = tile[tx][r];
    int p = __builtin_amdgcn_cvt_pk_fp8_f32(v, v, 0, false);
    outT[(size_t)(bx + r) * R + by + tx] = (unsigned char)(p & 0xff);
  }
}

// ---------------------------------------------------------------------------
// Angles: wave-per-row dot product. angles[row][k] = ctrl(row).enc_W[:,k] + b
// ---------------------------------------------------------------------------
__global__ __launch_bounds__(256) void angles_kernel(
    const float* __restrict__ z,
    const float* __restrict__ enc_W,  // (2048,6)
    const float* __restrict__ enc_b,  // (6,)
    float* __restrict__ angles) {     // (2048,6)
  int w = threadIdx.x >> 6, lane = threadIdx.x & 63;
  int row = blockIdx.x * 4 + w;
  const float* zrow = z + (size_t)row * ZD;
  float pa[6] = {0.f, 0.f, 0.f, 0.f, 0.f, 0.f};
#pragma unroll
  for (int t = 0; t < 32; t++) {
    int j = t * 64 + lane;
    float c = (j < 1024) ? zrow[1024 + j] : zrow[j - 1024];
    const float* wp = enc_W + j * 6;
#pragma unroll
    for (int k = 0; k < 6; k++) pa[k] += c * wp[k];
  }
#pragma unroll
  for (int k = 0; k < 6; k++)
    for (int off = 32; off > 0; off >>= 1) pa[k] += __shfl_down(pa[k], off, 64);
  if (lane == 0) {
#pragma unroll
    for (int k = 0; k < 6; k++) angles[row * 6 + k] = pa[k] + enc_b[k];
  }
}

// ---------------------------------------------------------------------------
// Statevector sim: one batch row per lane, 64 amplitudes in registers.
// ---------------------------------------------------------------------------
__global__ __launch_bounds__(64) void sim_kernel(
    const float* __restrict__ angles,  // (2048,6)
    const float* __restrict__ thetas,  // (3,6)
    const float* __restrict__ gain,
    const float* __restrict__ shift,
    float* __restrict__ acc) {
  int row = blockIdx.x * 64 + threadIdx.x;
  const float* a = angles + row * 6;

  float s[64];
#pragma unroll
  for (int i = 0; i < 64; i++) s[i] = 0.f;
  s[0] = 1.f;

#pragma unroll
  for (int k = 0; k < 6; k++) {
    float half = 0.5f * a[k];
    float c = cosf(half), si = sinf(half);
    int m = 1 << (5 - k);
#pragma unroll
    for (int i = 0; i < 64; i++) {
      if ((i & m) == 0) {
        float a0 = s[i], a1 = s[i | m];
        s[i] = c * a0 - si * a1;
        s[i | m] = si * a0 + c * a1;
      }
    }
  }
#pragma unroll
  for (int l = 0; l < 3; l++) {
#pragma unroll
    for (int k = 0; k < 6; k++) {
      float half = 0.5f * thetas[l * 6 + k];
      float c = cosf(half), si = sinf(half);
      int m = 1 << (5 - k);
#pragma unroll
      for (int i = 0; i < 64; i++) {
        if ((i & m) == 0) {
          float a0 = s[i], a1 = s[i | m];
          s[i] = c * a0 - si * a1;
          s[i | m] = si * a0 + c * a1;
        }
      }
    }
#pragma unroll
    for (int i = 0; i < 64; i++) {
      int rot = ((i << 1) | (i >> 5)) & 63;
      if (__popc(i & rot) & 1) s[i] = -s[i];
    }
  }

  float val = 0.f;
#pragma unroll
  for (int i = 0; i < 64; i++) {
    float zo = (6.f - 2.f * (float)__popc(i)) * (1.f / 6.f);
    val += s[i] * s[i] * zo;
  }
  float sg = softplus_f(gain[0]);
  float ss = softplus_f(shift[0]);
  float adj = softplus_f(sg * val - ss);
  for (int off = 32; off > 0; off >>= 1) adj += __shfl_down(adj, off, 64);
  if (threadIdx.x == 0) atomicAdd(acc, adj);
}

// ---------------------------------------------------------------------------
// dt scalar chain
// ---------------------------------------------------------------------------
__global__ void dt_kernel(const float* __restrict__ acc,
                          const float* __restrict__ cap_param,
                          const float* __restrict__ time_bias,
                          const float* __restrict__ last_stable,
                          float* __restrict__ dt_out) {
  float raw = acc[0] * (1.f / (float)NB) + time_bias[0];
  float cap = fmaxf(softplus_f(cap_param[0]), 1e-6f);
  float evo = cap / (1.f + expf(-raw / cap));
  if (!isfinite(evo)) evo = cap / (1.f + expf(-time_bias[0] / cap));
  float prev = fmaxf(last_stable[0], 1e-6f);
  float cand = fmaxf(evo, 1e-6f);
  float max_step = fmaxf(prev * 0.1f, 1e-4f);
  cand = fminf(cand, prev + max_step);
  cand = fminf(cand, 0.05f);
  dt_out[0] = isfinite(cand) ? cand : prev;
}

// ---------------------------------------------------------------------------
// fp8 MFMA GEMM, VGPR-staged classic pipeline: C = epi(A[M,K] @ Bt[N,K]^T)
// Block 128x64, 256 thr = 4 waves (2x2; wave-tile 64x32 = 4x2 of 16x16x32
// fp8_fp8 MFMA). BK=64, double-buffered LDS (24 KiB).
// KEY: staging goes global->VGPR->LDS (NOT global_load_lds), so the barrier
// needs only lgkmcnt — the vmcnt wait sits after the MFMA phase, giving a
// full compute phase of load-latency coverage. One __syncthreads per iter.
// LDS: row m holds 8 sub-chunks of 8B; sub-chunk c stored at slot (c+m)&7
//  -> <=2-way (free) conflicts for ds_write_b64 and ds_read_b64 frags.
// Scales: weights carry x16; EPI folds 1/16. g2/g1 carry x32 (range fit).
// EPI: 0 f32 partial (split-K) | 1 fp8 tanh(v/16+bias)
//      2 fp8 32*(1-t^2)*w3[col], t=tanh(v/16+bias)
//      3 fp8 (v/16)*(1-h^2), h=fp8 aux[row,col]
// ---------------------------------------------------------------------------
template <int EPI>
__global__ __launch_bounds__(256, 2) void mfma_gemm8(
    const unsigned char* __restrict__ A, int lda,
    const unsigned char* __restrict__ Bt, int ldb,
    void* __restrict__ Cv, int ldc,
    const float* __restrict__ bias,
    const float* __restrict__ w3,
    const unsigned char* __restrict__ aux, int ldaux,
    int Kslice) {
  __shared__ __align__(16) unsigned char sA[2 * 128 * 64];
  __shared__ __align__(16) unsigned char sB[2 * 64 * 64];

  const int tid = threadIdx.x;
  const int lane = tid & 63;
  const int w = tid >> 6;            // 0..3
  const int wm = w & 1, wn = w >> 1; // wave-tile: rows wm*64+, cols wn*32+
  const int row0 = blockIdx.y * 128;
  const int col0 = blockIdx.x * 64;
  const int koff = blockIdx.z * Kslice;

  // staging assignment: A chunks c16 = tid, 256+tid ; B chunk c16 = tid
  const int mA0 = tid >> 2, cpA0 = tid & 3;
  const int mA1 = (256 + tid) >> 2, cpA1 = tid & 3;
  const int mB0 = tid >> 2, cpB0 = tid & 3;
  const unsigned char* gA0 = A + (size_t)(row0 + mA0) * lda + koff + cpA0 * 16;
  const unsigned char* gA1 = A + (size_t)(row0 + mA1) * lda + koff + cpA1 * 16;
  const unsigned char* gB0 = Bt + (size_t)(col0 + mB0) * ldb + koff + cpB0 * 16;
  // LDS write offsets (two b64 slots per 16B chunk)
  const int wA0a = mA0 * 64 + (((2 * cpA0) + mA0) & 7) * 8;
  const int wA0b = mA0 * 64 + (((2 * cpA0 + 1) + mA0) & 7) * 8;
  const int wA1a = mA1 * 64 + (((2 * cpA1) + mA1) & 7) * 8;
  const int wA1b = mA1 * 64 + (((2 * cpA1 + 1) + mA1) & 7) * 8;
  const int wB0a = mB0 * 64 + (((2 * cpB0) + mB0) & 7) * 8;
  const int wB0b = mB0 * 64 + (((2 * cpB0 + 1) + mB0) & 7) * 8;

  // fragment read offsets (k0-invariant)
  const int q = lane >> 4, r = lane & 15;
  int aoff[4][2], boff[2][2];
#pragma unroll
  for (int i = 0; i < 4; i++) {
    int ma = wm * 64 + i * 16 + r;
#pragma unroll
    for (int h = 0; h < 2; h++)
      aoff[i][h] = ma * 64 + (((h * 4 + q) + ma) & 7) * 8;
  }
#pragma unroll
  for (int j = 0; j < 2; j++) {
    int mb = wn * 32 + j * 16 + r;
#pragma unroll
    for (int h = 0; h < 2; h++)
      boff[j][h] = mb * 64 + (((h * 4 + q) + mb) & 7) * 8;
  }

  f32x4 acc[4][2] = {};

  // load tile 0 -> regs -> LDS buf0
  f32x4 rA0 = *(const f32x4*)gA0;
  f32x4 rA1 = *(const f32x4*)gA1;
  f32x4 rB0 = *(const f32x4*)gB0;
  *(long long*)(sA + wA0a) = ((const long long*)&rA0)[0];
  *(long long*)(sA + wA0b) = ((const long long*)&rA0)[1];
  *(long long*)(sA + wA1a) = ((const long long*)&rA1)[0];
  *(long long*)(sA + wA1b) = ((const long long*)&rA1)[1];
  *(long long*)(sB + wB0a) = ((const long long*)&rB0)[0];
  *(long long*)(sB + wB0b) = ((const long long*)&rB0)[1];
  __syncthreads();

  int cur = 0;
  for (int k0 = 0; k0 < Kslice; k0 += 64) {
    const bool more = (k0 + 64 < Kslice);
    if (more) {  // issue next-tile loads (covered by the MFMA phase below)
      rA0 = *(const f32x4*)(gA0 + k0 + 64);
      rA1 = *(const f32x4*)(gA1 + k0 + 64);
      rB0 = *(const f32x4*)(gB0 + k0 + 64);
    }

    const unsigned char* bA = sA + cur * (128 * 64);
    const unsigned char* bB = sB + cur * (64 * 64);
#pragma unroll
    for (int h = 0; h < 2; h++) {
      long long af[4], bf[2];
#pragma unroll
      for (int i = 0; i < 4; i++) af[i] = *(const long long*)(bA + aoff[i][h]);
#pragma unroll
      for (int j = 0; j < 2; j++) bf[j] = *(const long long*)(bB + boff[j][h]);
#pragma unroll
      for (int i = 0; i < 4; i++)
#pragma unroll
        for (int j = 0; j < 2; j++)
          acc[i][j] = __builtin_amdgcn_mfma_f32_16x16x32_fp8_fp8(
              af[i], bf[j], acc[i][j], 0, 0, 0);
    }

    if (more) {  // ds_write next tile (vmcnt wait lands here, post-MFMA)
      unsigned char* nA = sA + (cur ^ 1) * (128 * 64);
      unsigned char* nB = sB + (cur ^ 1) * (64 * 64);
      *(long long*)(nA + wA0a) = ((const long long*)&rA0)[0];
      *(long long*)(nA + wA0b) = ((const long long*)&rA0)[1];
      *(long long*)(nA + wA1a) = ((const long long*)&rA1)[0];
      *(long long*)(nA + wA1b) = ((const long long*)&rA1)[1];
      *(long long*)(nB + wB0a) = ((const long long*)&rB0)[0];
      *(long long*)(nB + wB0b) = ((const long long*)&rB0)[1];
    }
    __syncthreads();  // lgkmcnt only — no global drain
    cur ^= 1;
  }

  // epilogue: C/D layout col=lane&15, row=(lane>>4)*4+reg
  float* Cf = (float*)Cv;
  unsigned char* C8 = (unsigned char*)Cv;
  float* Pz = Cf + (size_t)blockIdx.z * (size_t)gridDim.y * 128 * ldc;

#pragma unroll
  for (int i = 0; i < 4; i++) {
    int rowb = row0 + wm * 64 + i * 16 + q * 4;
#pragma unroll
    for (int j = 0; j < 2; j++) {
      int col = col0 + wn * 32 + j * 16 + r;
      if (EPI == 0) {
#pragma unroll
        for (int g = 0; g < 4; g++)
          Pz[(size_t)(rowb + g) * ldc + col] = acc[i][j][g];
      } else {
        float o[4];
#pragma unroll
        for (int g = 0; g < 4; g++) {
          float v = acc[i][j][g] * 0.0625f;  // undo weight x16
          if (EPI == 1) {
            o[g] = tanhf(v + bias[col]);
          } else if (EPI == 2) {
            float t = tanhf(v + bias[col]);
            o[g] = 32.f * (1.f - t * t) * w3[col];
          } else {
            float h = fp8_to_f32(aux[(size_t)(rowb + g) * ldaux + col]);
            o[g] = v * (1.f - h * h);
          }
        }
        int p = pack_fp8x4(o[0], o[1], o[2], o[3]);
#pragma unroll
        for (int g = 0; g < 4; g++)
          C8[(size_t)(rowb + g) * ldc + col] =
              (unsigned char)((p >> (8 * g)) & 0xff);
      }
    }
  }
}

// ---------------------------------------------------------------------------
// bf16 MFMA GEMM (W_out only, precision-critical): f32 split-K partials.
// Round-6 structure: 128x64 tile, 4 waves, BK=64, global_load_lds dbuf.
// ---------------------------------------------------------------------------
__global__ __launch_bounds__(256, 2) void mfma_gemm_bf16(
    const __bf16* __restrict__ A, int lda,
    const __bf16* __restrict__ Bt, int ldb,
    float* __restrict__ P, int ldc,
    int Kslice) {
  __shared__ __bf16 sA[2][128 * 64];
  __shared__ __bf16 sB[2][64 * 64];

  const int tid = threadIdx.x;
  const int lane = tid & 63;
  const int w = tid >> 6;
  const int wm = w & 1, wn = w >> 1;
  const int row0 = blockIdx.y * 128;
  const int col0 = blockIdx.x * 64;
  const int koff = blockIdx.z * Kslice;

  const __bf16* gA[4]; int lofA[4];
  const __bf16* gB[2]; int lofB[2];
#pragma unroll
  for (int i = 0; i < 4; i++) {
    int c = i * 256 + tid;
    int m = c >> 3, cc = c & 7;
    int o = cc ^ (m & 7);
    gA[i] = A + (size_t)(row0 + m) * lda + koff + o * 8;
    lofA[i] = c * 8;
  }
#pragma unroll
  for (int i = 0; i < 2; i++) {
    int c = i * 256 + tid;
    int m = c >> 3, cc = c & 7;
    int o = cc ^ (m & 7);
    gB[i] = Bt + (size_t)(col0 + m) * ldb + koff + o * 8;
    lofB[i] = c * 8;
  }

  const int q = lane >> 4, r = lane & 15;
  int aoff[4][2], boff[2][2];
#pragma unroll
  for (int i = 0; i < 4; i++) {
    int ma = wm * 64 + i * 16 + r;
#pragma unroll
    for (int h = 0; h < 2; h++)
      aoff[i][h] = (ma * 8 + ((h * 4 + q) ^ (ma & 7))) * 8;
  }
#pragma unroll
  for (int j = 0; j < 2; j++) {
    int mb = wn * 32 + j * 16 + r;
#pragma unroll
    for (int h = 0; h < 2; h++)
      boff[j][h] = (mb * 8 + ((h * 4 + q) ^ (mb & 7))) * 8;
  }

  f32x4 acc[4][2] = {};

#pragma unroll
  for (int i = 0; i < 4; i++) gload_lds16(gA[i], &sA[0][0] + lofA[i]);
#pragma unroll
  for (int i = 0; i < 2; i++) gload_lds16(gB[i], &sB[0][0] + lofB[i]);

  int cur = 0;
  for (int k0 = 0; k0 < Kslice; k0 += 64) {
    __syncthreads();
    if (k0 + 64 < Kslice) {
      int nxt = cur ^ 1;
#pragma unroll
      for (int i = 0; i < 4; i++)
        gload_lds16(gA[i] + k0 + 64, &sA[nxt][0] + lofA[i]);
#pragma unroll
      for (int i = 0; i < 2; i++)
        gload_lds16(gB[i] + k0 + 64, &sB[nxt][0] + lofB[i]);
    }
#pragma unroll
    for (int h = 0; h < 2; h++) {
      bf16x8 af[4], bfr[2];
#pragma unroll
      for (int i = 0; i < 4; i++)
        af[i] = *(const bf16x8*)(&sA[cur][0] + aoff[i][h]);
#pragma unroll
      for (int j = 0; j < 2; j++)
        bfr[j] = *(const bf16x8*)(&sB[cur][0] + boff[j][h]);
#pragma unroll
      for (int i = 0; i < 4; i++)
#pragma unroll
        for (int j = 0; j < 2; j++)
          acc[i][j] = __builtin_amdgcn_mfma_f32_16x16x32_bf16(af[i], bfr[j],
                                                              acc[i][j], 0, 0, 0);
    }
    cur ^= 1;
  }

  float* Pz = P + (size_t)blockIdx.z * (size_t)gridDim.y * 128 * ldc;
#pragma unroll
  for (int i = 0; i < 4; i++) {
    int rowb = row0 + wm * 64 + i * 16 + q * 4;
#pragma unroll
    for (int j = 0; j < 2; j++) {
      int col = col0 + wn * 32 + j * 16 + r;
#pragma unroll
      for (int g = 0; g < 4; g++)
        Pz[(size_t)(rowb + g) * ldc + col] = acc[i][j][g];
    }
  }
}

// ---------------------------------------------------------------------------
// grad = sum of 4 split-K partials (scaled 1/512 for fp8 weight/act scales);
// z[:, off:off+512] += coef*dt*grad ; refresh zb (bf16) and zf8 (fp8).
// ---------------------------------------------------------------------------
__global__ void update_kernel(float* __restrict__ z, __bf16* __restrict__ zb,
                              unsigned char* __restrict__ zf8,
                              const float* __restrict__ gp,
                              const float* __restrict__ dt,
                              float coef, int off) {
  int t = blockIdx.x * blockDim.x + threadIdx.x;  // 0 .. NB*SD/4
  int b = t >> 7;
  int j4 = t & 127;
  const f32x4* g4 = (const f32x4*)gp;
  constexpr int STRIDE = NB * SD / 4;
  f32x4 g = g4[t] + g4[t + STRIDE] + g4[t + 2 * STRIDE] + g4[t + 3 * STRIDE];
  int zi4 = (b * ZD + off) / 4 + j4;
  f32x4 v = ((f32x4*)z)[zi4];
  float s = coef * dt[0] * (1.f / 512.f);  // undo x16(w) * x32(g1)
  v[0] += s * g[0]; v[1] += s * g[1]; v[2] += s * g[2]; v[3] += s * g[3];
  ((f32x4*)z)[zi4] = v;
  bf16x4 o;
  o[0] = (__bf16)v[0]; o[1] = (__bf16)v[1];
  o[2] = (__bf16)v[2]; o[3] = (__bf16)v[3];
  ((bf16x4*)zb)[zi4] = o;
  ((int*)zf8)[zi4] = pack_fp8x4(v[0], v[1], v[2], v[3]);
}

// ---------------------------------------------------------------------------
// W_out split-K=2 reduce + bias (f32, x4 vec)
// ---------------------------------------------------------------------------
__global__ void wout_reduce(const float* __restrict__ gp,
                            const float* __restrict__ b_out,
                            float* __restrict__ out) {
  int t = blockIdx.x * blockDim.x + threadIdx.x;  // 0 .. NB*1024/4
  constexpr int S = NB * 1024 / 4;
  const f32x4* g4 = (const f32x4*)gp;
  f32x4 v = g4[t] + g4[t + S];
  f32x4 bb = ((const f32x4*)b_out)[t & 255];
  v[0] += bb[0]; v[1] += bb[1]; v[2] += bb[2]; v[3] += bb[3];
  ((f32x4*)out)[t] = v;
}

// ---------------------------------------------------------------------------
// h_next: first 8 slices = z[:, :1024] (exact f32), rest zero
// ---------------------------------------------------------------------------
__global__ void hnext_kernel(const float* __restrict__ z,
                             float* __restrict__ out) {
  int t = blockIdx.x * blockDim.x + threadIdx.x;
  int i4 = t & 511;
  f32x4 zero = {0.f, 0.f, 0.f, 0.f};
  ((f32x4*)out)[t] = (i4 < 256) ? ((const f32x4*)z)[t] : zero;
}

// ---------------------------------------------------------------------------
extern "C" void kernel_launch(void* const* d_in, const int* in_sizes, int n_in,
                              void* d_out, int out_size, void* d_ws,
                              size_t ws_size, hipStream_t stream) {
  const float* x        = (const float*)d_in[0];
  const float* h_padded = (const float*)d_in[1];
  const float* W1    = (const float*)d_in[3];
  const float* b1    = (const float*)d_in[4];
  const float* W2    = (const float*)d_in[5];
  const float* b2    = (const float*)d_in[6];
  const float* W3    = (const float*)d_in[7];
  const float* W_out = (const float*)d_in[9];
  const float* b_out = (const float*)d_in[10];
  const float* enc_W = (const float*)d_in[11];
  const float* enc_b = (const float*)d_in[12];
  const float* thetas = (const float*)d_in[13];
  const float* gain   = (const float*)d_in[14];
  const float* shift  = (const float*)d_in[15];
  const float* cap_p  = (const float*)d_in[16];
  const float* t_bias = (const float*)d_in[17];
  const float* l_stab = (const float*)d_in[18];

  float* out_mat  = (float*)d_out;              // (2048,1024)
  float* out_hnxt = (float*)d_out + NB * 1024;  // (2048,16,128)

  // workspace layout (bytes)
  char* base = (char*)d_ws;
  float* z      = (float*)(base);                      // 16MB f32
  float* part   = (float*)(base + 16 * MB_);           // 16MB f32 partials
  __bf16* zb    = (__bf16*)(base + 32 * MB_);          // 8MB bf16
  __bf16* Wot   = (__bf16*)(base + 40 * MB_);          // 2MB bf16
  float* angl   = (float*)(base + 42 * MB_);           // 48KB
  float* accp   = (float*)(base + 42 * MB_ + 65536);   // scalars
  float* dtp    = accp + 1;
  unsigned char* zf8  = (unsigned char*)(base + 43 * MB_);  // 4MB each:
  unsigned char* h1_8 = zf8 + (size_t)NELEM_Z;
  unsigned char* g2_8 = h1_8 + (size_t)NELEM_Z;
  unsigned char* g1_8 = g2_8 + (size_t)NELEM_Z;
  unsigned char* W1n8 = g1_8 + (size_t)NELEM_Z;
  unsigned char* W1t8 = W1n8 + (size_t)NELEM_Z;
  unsigned char* W2n8 = W1t8 + (size_t)NELEM_Z;
  unsigned char* W2t8 = W2n8 + (size_t)NELEM_Z;

  dim3 thr256(256);
  dim3 thrT(32, 8);

  // 1. weight prep: fp8 (straight + transposed, x16) and bf16 W_out^T
  prep_w8<<<dim3(64, 64), thrT, 0, stream>>>(W1, W1n8, W1t8, ZD, ZD);
  prep_w8<<<dim3(64, 64), thrT, 0, stream>>>(W2, W2n8, W2t8, ZD, ZD);
  prep_w<<<dim3(32, 32), thrT, 0, stream>>>(W_out, Wot, 1024, 1024);

  // 2. build z (f32 + bf16 + fp8) + zero acc
  build_z_kernel<<<dim3(NELEM_Z / 4 / 256), thr256, 0, stream>>>(
      x, h_padded, z, zb, zf8, accp);
  // 3. VQC + dt
  angles_kernel<<<dim3(NB / 4), thr256, 0, stream>>>(z, enc_W, enc_b, angl);
  sim_kernel<<<dim3(NB / 64), dim3(64), 0, stream>>>(angl, thetas, gain, shift,
                                                     accp);
  dt_kernel<<<dim3(1), dim3(1), 0, stream>>>(accp, cap_p, t_bias, l_stab, dtp);

  // 4. three leapfrog gradient evaluations (all-fp8 grad path)
  const int   j0r[3]  = {0, 512, 0};
  const int   offs[3] = {512, 0, 512};
  const float coef[3] = {-0.5f, 1.0f, -0.5f};

  dim3 gridSq(32, 16, 1);   // 2048x2048, 128x64 tiles -> 512 blocks (2/CU)
  dim3 gridGr(8, 16, 4);    // 2048x512, split-K=4     -> 512 blocks

  for (int i = 0; i < 3; i++) {
    // h1 = tanh(z @ W1 + b1)                       (fp8 out)
    mfma_gemm8<1><<<gridSq, thr256, 0, stream>>>(
        zf8, ZD, W1t8, ZD, h1_8, ZD, b1, nullptr, nullptr, 0, ZD);
    // g2 = 32*(1 - tanh(h1 @ W2 + b2)^2) * W3[col] (fp8 out)
    mfma_gemm8<2><<<gridSq, thr256, 0, stream>>>(
        h1_8, ZD, W2t8, ZD, g2_8, ZD, b2, W3, nullptr, 0, ZD);
    // g1 = (g2 @ W2^T)/16 * (1 - h1^2)             (fp8 out, carries x32)
    mfma_gemm8<3><<<gridSq, thr256, 0, stream>>>(
        g2_8, ZD, W2n8, ZD, g1_8, ZD, nullptr, nullptr, h1_8, ZD, ZD);
    // part = g1 @ W1[j0:j0+512,:]^T  (f32 partials, split-K=4)
    mfma_gemm8<0><<<gridGr, thr256, 0, stream>>>(
        g1_8, ZD, W1n8 + (size_t)j0r[i] * ZD, ZD, part, SD, nullptr, nullptr,
        nullptr, 0, 512);
    // z[:, offs] += coef*dt*sum(part)/512
    update_kernel<<<dim3(NB * SD / 4 / 256), thr256, 0, stream>>>(
        z, zb, zf8, part, dtp, coef[i], offs[i]);
  }

  // 5. out = z[:, :1024] @ W_out + b_out  (bf16, split-K=2 + reduce)
  mfma_gemm_bf16<<<dim3(16, 16, 2), thr256, 0, stream>>>(zb, ZD, Wot, 1024,
                                                         part, 1024, 512);
  wout_reduce<<<dim3(NB * 1024 / 4 / 256), thr256, 0, stream>>>(part, b_out,
                                                                out_mat);

  // 6. h_next writeback
  hnext_kernel<<<dim3(NELEM_Z / 4 / 256), thr256, 0, stream>>>(z, out_hnxt);
}

// Round 8
// 445.867 us; speedup vs baseline: 8.3258x; 1.0798x over previous
//
#include <hip/hip_runtime.h>
#include <math.h>

// Problem constants
#define NB 2048            // batch
#define ZD 2048            // z dim = 2*512 + 1024, also D_H
#define SD 512             // state dim
#define NELEM_Z (NB * ZD)  // 4194304
#define MB_ (1024 * 1024)

typedef float f32x4 __attribute__((ext_vector_type(4)));
typedef __bf16 bf16x8 __attribute__((ext_vector_type(8)));
typedef __bf16 bf16x4 __attribute__((ext_vector_type(4)));
typedef long long i64;

__device__ __forceinline__ float softplus_f(float x) {
  if (x > 20.f) return x;
  if (x < -20.f) return expf(x);
  return log1pf(expf(x));
}

__device__ __forceinline__ void gload_lds16(const __bf16* g, __bf16* l) {
  __builtin_amdgcn_global_load_lds(
      (__attribute__((address_space(1))) void*)(g),
      (__attribute__((address_space(3))) void*)(l), 16, 0, 0);
}

// pack 4 floats -> 4 fp8 e4m3 bytes (OCP on gfx950)
__device__ __forceinline__ int pack_fp8x4(float a, float b, float c, float d) {
  int p = __builtin_amdgcn_cvt_pk_fp8_f32(a, b, 0, false);
  p = __builtin_amdgcn_cvt_pk_fp8_f32(c, d, p, true);
  return p;
}
__device__ __forceinline__ float fp8_to_f32(unsigned char b) {
  return __builtin_amdgcn_cvt_f32_fp8((int)b, 0);
}

// ---------------------------------------------------------------------------
// Build z = [q,p,x] (f32 + bf16 + fp8 mirrors) AND the VQC encoder angles
// fused: one block per batch row; 4 waves reduce the 2048-elem dot products.
// ctrl[j] = (j<1024) ? z[1024+j] : z[j-1024]
// ---------------------------------------------------------------------------
__global__ __launch_bounds__(256) void build_z_kernel(
    const float* __restrict__ x,
    const float* __restrict__ h_padded,
    const float* __restrict__ enc_W,  // (2048,6)
    const float* __restrict__ enc_b,  // (6,)
    float* __restrict__ z,
    __bf16* __restrict__ zb,
    unsigned char* __restrict__ zf8,
    float* __restrict__ angles,       // (2048,6)
    float* __restrict__ acc) {
  int b = blockIdx.x;
  int tid = threadIdx.x;
  if (b == 0 && tid == 0) acc[0] = 0.f;
  int lane = tid & 63, w = tid >> 6;
  __shared__ float red[4][6];

  float pa[6] = {0.f, 0.f, 0.f, 0.f, 0.f, 0.f};
#pragma unroll
  for (int cc = 0; cc < 2; cc++) {
    int c = cc * 256 + tid;  // f32x4 chunk 0..511 within the row
    int i = c * 4;           // element index in z-row
    f32x4 v = (i < 1024) ? ((const f32x4*)(h_padded + (size_t)b * 2048))[c]
                         : ((const f32x4*)(x + (size_t)b * 1024))[c - 256];
    size_t zi = (size_t)b * 512 + c;
    ((f32x4*)z)[zi] = v;
    bf16x4 o;
    o[0] = (__bf16)v[0]; o[1] = (__bf16)v[1];
    o[2] = (__bf16)v[2]; o[3] = (__bf16)v[3];
    ((bf16x4*)zb)[zi] = o;
    ((int*)zf8)[zi] = pack_fp8x4(v[0], v[1], v[2], v[3]);
    int cj = (i < 1024) ? (1024 + i) : (i - 1024);  // ctrl index of v[0]
#pragma unroll
    for (int e = 0; e < 4; e++) {
      const float* wp = enc_W + (size_t)(cj + e) * 6;
#pragma unroll
      for (int k = 0; k < 6; k++) pa[k] += v[e] * wp[k];
    }
  }
#pragma unroll
  for (int k = 0; k < 6; k++)
    for (int off = 32; off > 0; off >>= 1) pa[k] += __shfl_down(pa[k], off, 64);
  if (lane == 0) {
#pragma unroll
    for (int k = 0; k < 6; k++) red[w][k] = pa[k];
  }
  __syncthreads();
  if (tid < 6)
    angles[b * 6 + tid] =
        red[0][tid] + red[1][tid] + red[2][tid] + red[3][tid] + enc_b[tid];
}

// ---------------------------------------------------------------------------
// bf16 weight prep (for W_out): f32 (R x C) -> transposed bf16 (C x R)
// ---------------------------------------------------------------------------
__global__ void prep_w(const float* __restrict__ in,
                       __bf16* __restrict__ outT, int R, int C) {
  __shared__ float tile[32][33];
  int bx = blockIdx.x * 32, by = blockIdx.y * 32;
  int tx = threadIdx.x, ty = threadIdx.y;
  for (int r = ty; r < 32; r += 8)
    tile[r][tx] = in[(size_t)(by + r) * C + bx + tx];
  __syncthreads();
  for (int r = ty; r < 32; r += 8)
    outT[(size_t)(bx + r) * R + by + tx] = (__bf16)tile[tx][r];
}

// ---------------------------------------------------------------------------
// fp8 weight prep: f32 (R x C) -> straight fp8 and transposed fp8, x16 scale.
// ---------------------------------------------------------------------------
__global__ void prep_w8(const float* __restrict__ in,
                        unsigned char* __restrict__ outN,
                        unsigned char* __restrict__ outT, int R, int C) {
  __shared__ float tile[32][33];
  int bx = blockIdx.x * 32, by = blockIdx.y * 32;
  int tx = threadIdx.x, ty = threadIdx.y;
  for (int r = ty; r < 32; r += 8) {
    float v = in[(size_t)(by + r) * C + bx + tx] * 16.f;
    tile[r][tx] = v;
    int p = __builtin_amdgcn_cvt_pk_fp8_f32(v, v, 0, false);
    outN[(size_t)(by + r) * C + bx + tx] = (unsigned char)(p & 0xff);
  }
  __syncthreads();
  for (int r = ty; r < 32; r += 8) {
    float v = tile[tx][r];
    int p = __builtin_amdgcn_cvt_pk_fp8_f32(v, v, 0, false);
    outT[(size_t)(bx + r) * R + by + tx] = (unsigned char)(p & 0xff);
  }
}

// ---------------------------------------------------------------------------
// Statevector sim: one batch row per lane, 64 amplitudes in registers.
// ---------------------------------------------------------------------------
__global__ __launch_bounds__(64) void sim_kernel(
    const float* __restrict__ angles,  // (2048,6)
    const float* __restrict__ thetas,  // (3,6)
    const float* __restrict__ gain,
    const float* __restrict__ shift,
    float* __restrict__ acc) {
  int row = blockIdx.x * 64 + threadIdx.x;
  const float* a = angles + row * 6;

  float s[64];
#pragma unroll
  for (int i = 0; i < 64; i++) s[i] = 0.f;
  s[0] = 1.f;

#pragma unroll
  for (int k = 0; k < 6; k++) {
    float half = 0.5f * a[k];
    float c = cosf(half), si = sinf(half);
    int m = 1 << (5 - k);
#pragma unroll
    for (int i = 0; i < 64; i++) {
      if ((i & m) == 0) {
        float a0 = s[i], a1 = s[i | m];
        s[i] = c * a0 - si * a1;
        s[i | m] = si * a0 + c * a1;
      }
    }
  }
#pragma unroll
  for (int l = 0; l < 3; l++) {
#pragma unroll
    for (int k = 0; k < 6; k++) {
      float half = 0.5f * thetas[l * 6 + k];
      float c = cosf(half), si = sinf(half);
      int m = 1 << (5 - k);
#pragma unroll
      for (int i = 0; i < 64; i++) {
        if ((i & m) == 0) {
          float a0 = s[i], a1 = s[i | m];
          s[i] = c * a0 - si * a1;
          s[i | m] = si * a0 + c * a1;
        }
      }
    }
#pragma unroll
    for (int i = 0; i < 64; i++) {
      int rot = ((i << 1) | (i >> 5)) & 63;
      if (__popc(i & rot) & 1) s[i] = -s[i];
    }
  }

  float val = 0.f;
#pragma unroll
  for (int i = 0; i < 64; i++) {
    float zo = (6.f - 2.f * (float)__popc(i)) * (1.f / 6.f);
    val += s[i] * s[i] * zo;
  }
  float sg = softplus_f(gain[0]);
  float ss = softplus_f(shift[0]);
  float adj = softplus_f(sg * val - ss);
  for (int off = 32; off > 0; off >>= 1) adj += __shfl_down(adj, off, 64);
  if (threadIdx.x == 0) atomicAdd(acc, adj);
}

// ---------------------------------------------------------------------------
// dt scalar chain
// ---------------------------------------------------------------------------
__global__ void dt_kernel(const float* __restrict__ acc,
                          const float* __restrict__ cap_param,
                          const float* __restrict__ time_bias,
                          const float* __restrict__ last_stable,
                          float* __restrict__ dt_out) {
  float raw = acc[0] * (1.f / (float)NB) + time_bias[0];
  float cap = fmaxf(softplus_f(cap_param[0]), 1e-6f);
  float evo = cap / (1.f + expf(-raw / cap));
  if (!isfinite(evo)) evo = cap / (1.f + expf(-time_bias[0] / cap));
  float prev = fmaxf(last_stable[0], 1e-6f);
  float cand = fmaxf(evo, 1e-6f);
  float max_step = fmaxf(prev * 0.1f, 1e-4f);
  cand = fminf(cand, prev + max_step);
  cand = fminf(cand, 0.05f);
  dt_out[0] = isfinite(cand) ? cand : prev;
}

// ---------------------------------------------------------------------------
// fp8 MFMA GEMM v2: C = epi(A[M,K] @ Bt[N,K]^T)
// Block 128x64, 256 thr = 4 waves (2x2; wave-tile 64x32 = 4x2 of 16x16x32
// fp8_fp8 MFMA). BK=128 (16 iters at K=2048 -> MFMA phase ~1200cyc/CU-iter
// covers the 900cyc HBM load latency even through the barrier's vmcnt drain;
// half the barrier count of BK=64). VGPR-staged dbuf LDS (54 KiB, 2 blk/CU).
// LDS layout: row stride 144B (odd dword phase -> bank rotation). k-bytes
// interleaved pos = q*32 + (h>>1)*16 + (h&1)*8 + b  so one ds_read_b128 at
// (row*144 + q*32 + H*16) yields the lane's fragments for h=2H and 2H+1.
// Bank check: reads hit 8 lanes per 4-bank quad (uniform, 8-cyc floor).
// Scales: weights x16 (EPI folds 1/16); g2 carries x32.
// EPI: 0 f32 partial (split-K) | 1 fp8 tanh(v/16+bias)
//      2 fp8 32*(1-t^2)*w3[col] | 3 fp8 (v/16)*(1-h^2)
// ---------------------------------------------------------------------------
template <int EPI>
__global__ __launch_bounds__(256, 2) void mfma_gemm8(
    const unsigned char* __restrict__ A, int lda,
    const unsigned char* __restrict__ Bt, int ldb,
    void* __restrict__ Cv, int ldc,
    const float* __restrict__ bias,
    const float* __restrict__ w3,
    const unsigned char* __restrict__ aux, int ldaux,
    int Kslice) {
  __shared__ __align__(16) unsigned char sA[2][128 * 144];
  __shared__ __align__(16) unsigned char sB[2][64 * 144];

  const int tid = threadIdx.x;
  const int lane = tid & 63;
  const int w = tid >> 6;
  const int wm = w & 1, wn = w >> 1;
  const int row0 = blockIdx.y * 128;
  const int col0 = blockIdx.x * 64;
  const int koff = blockIdx.z * Kslice;

  // staging: A 4 chunks (16B), B 2 chunks per thread per BK=128 tile
  const unsigned char* gA[4]; int wA0[4], wA1[4];
  const unsigned char* gB[2]; int wB0[2], wB1[2];
#pragma unroll
  for (int i = 0; i < 4; i++) {
    int c = i * 256 + tid;
    int m = c >> 3, cp = c & 7;
    gA[i] = A + (size_t)(row0 + m) * lda + koff + cp * 16;
    int h = cp >> 1;
    int Hofs = (h >> 1) * 16 + (h & 1) * 8;
    wA0[i] = m * 144 + ((2 * cp) & 3) * 32 + Hofs;
    wA1[i] = m * 144 + ((2 * cp + 1) & 3) * 32 + Hofs;
  }
#pragma unroll
  for (int i = 0; i < 2; i++) {
    int c = i * 256 + tid;
    int m = c >> 3, cp = c & 7;
    gB[i] = Bt + (size_t)(col0 + m) * ldb + koff + cp * 16;
    int h = cp >> 1;
    int Hofs = (h >> 1) * 16 + (h & 1) * 8;
    wB0[i] = m * 144 + ((2 * cp) & 3) * 32 + Hofs;
    wB1[i] = m * 144 + ((2 * cp + 1) & 3) * 32 + Hofs;
  }

  // fragment read offsets (b128 covers h=2H and h=2H+1)
  const int q = lane >> 4, r = lane & 15;
  int aoff[4][2], boff[2][2];
#pragma unroll
  for (int i = 0; i < 4; i++) {
    int ma = wm * 64 + i * 16 + r;
#pragma unroll
    for (int H = 0; H < 2; H++) aoff[i][H] = ma * 144 + q * 32 + H * 16;
  }
#pragma unroll
  for (int j = 0; j < 2; j++) {
    int mb = wn * 32 + j * 16 + r;
#pragma unroll
    for (int H = 0; H < 2; H++) boff[j][H] = mb * 144 + q * 32 + H * 16;
  }

  f32x4 acc[4][2] = {};
  f32x4 rA[4], rB[2];

  // tile 0: global -> regs -> LDS buf0
#pragma unroll
  for (int i = 0; i < 4; i++) rA[i] = *(const f32x4*)gA[i];
#pragma unroll
  for (int i = 0; i < 2; i++) rB[i] = *(const f32x4*)gB[i];
#pragma unroll
  for (int i = 0; i < 4; i++) {
    *(i64*)(&sA[0][0] + wA0[i]) = ((const i64*)&rA[i])[0];
    *(i64*)(&sA[0][0] + wA1[i]) = ((const i64*)&rA[i])[1];
  }
#pragma unroll
  for (int i = 0; i < 2; i++) {
    *(i64*)(&sB[0][0] + wB0[i]) = ((const i64*)&rB[i])[0];
    *(i64*)(&sB[0][0] + wB1[i]) = ((const i64*)&rB[i])[1];
  }
  __syncthreads();

  int cur = 0;
  for (int k0 = 0; k0 < Kslice; k0 += 128) {
    const bool more = (k0 + 128 < Kslice);
    if (more) {  // next-tile loads: covered by the MFMA phase below
#pragma unroll
      for (int i = 0; i < 4; i++) rA[i] = *(const f32x4*)(gA[i] + k0 + 128);
#pragma unroll
      for (int i = 0; i < 2; i++) rB[i] = *(const f32x4*)(gB[i] + k0 + 128);
    }

    const unsigned char* bA = &sA[cur][0];
    const unsigned char* bB = &sB[cur][0];
#pragma unroll
    for (int H = 0; H < 2; H++) {
      i64 a0[4], a1[4], b0[2], b1[2];
#pragma unroll
      for (int i = 0; i < 4; i++) {
        f32x4 v = *(const f32x4*)(bA + aoff[i][H]);
        a0[i] = ((const i64*)&v)[0];
        a1[i] = ((const i64*)&v)[1];
      }
#pragma unroll
      for (int j = 0; j < 2; j++) {
        f32x4 v = *(const f32x4*)(bB + boff[j][H]);
        b0[j] = ((const i64*)&v)[0];
        b1[j] = ((const i64*)&v)[1];
      }
#pragma unroll
      for (int i = 0; i < 4; i++)
#pragma unroll
        for (int j = 0; j < 2; j++)
          acc[i][j] = __builtin_amdgcn_mfma_f32_16x16x32_fp8_fp8(
              a0[i], b0[j], acc[i][j], 0, 0, 0);
#pragma unroll
      for (int i = 0; i < 4; i++)
#pragma unroll
        for (int j = 0; j < 2; j++)
          acc[i][j] = __builtin_amdgcn_mfma_f32_16x16x32_fp8_fp8(
              a1[i], b1[j], acc[i][j], 0, 0, 0);
    }

    if (more) {  // ds_write next tile (vmcnt wait lands here, post-MFMA)
      unsigned char* nA = &sA[cur ^ 1][0];
      unsigned char* nB = &sB[cur ^ 1][0];
#pragma unroll
      for (int i = 0; i < 4; i++) {
        *(i64*)(nA + wA0[i]) = ((const i64*)&rA[i])[0];
        *(i64*)(nA + wA1[i]) = ((const i64*)&rA[i])[1];
      }
#pragma unroll
      for (int i = 0; i < 2; i++) {
        *(i64*)(nB + wB0[i]) = ((const i64*)&rB[i])[0];
        *(i64*)(nB + wB1[i]) = ((const i64*)&rB[i])[1];
      }
    }
    __syncthreads();
    cur ^= 1;
  }

  // epilogue: C/D layout col=lane&15, row=(lane>>4)*4+reg
  float* Cf = (float*)Cv;
  unsigned char* C8 = (unsigned char*)Cv;
  float* Pz = Cf + (size_t)blockIdx.z * (size_t)gridDim.y * 128 * ldc;

#pragma unroll
  for (int i = 0; i < 4; i++) {
    int rowb = row0 + wm * 64 + i * 16 + q * 4;
#pragma unroll
    for (int j = 0; j < 2; j++) {
      int col = col0 + wn * 32 + j * 16 + r;
      if (EPI == 0) {
#pragma unroll
        for (int g = 0; g < 4; g++)
          Pz[(size_t)(rowb + g) * ldc + col] = acc[i][j][g];
      } else {
        float o[4];
#pragma unroll
        for (int g = 0; g < 4; g++) {
          float v = acc[i][j][g] * 0.0625f;  // undo weight x16
          if (EPI == 1) {
            o[g] = tanhf(v + bias[col]);
          } else if (EPI == 2) {
            float t = tanhf(v + bias[col]);
            o[g] = 32.f * (1.f - t * t) * w3[col];
          } else {
            float h = fp8_to_f32(aux[(size_t)(rowb + g) * ldaux + col]);
            o[g] = v * (1.f - h * h);
          }
        }
        int p = pack_fp8x4(o[0], o[1], o[2], o[3]);
#pragma unroll
        for (int g = 0; g < 4; g++)
          C8[(size_t)(rowb + g) * ldc + col] =
              (unsigned char)((p >> (8 * g)) & 0xff);
      }
    }
  }
}

// ---------------------------------------------------------------------------
// bf16 MFMA GEMM (W_out only, precision-critical): f32 split-K partials.
// ---------------------------------------------------------------------------
__global__ __launch_bounds__(256, 2) void mfma_gemm_bf16(
    const __bf16* __restrict__ A, int lda,
    const __bf16* __restrict__ Bt, int ldb,
    float* __restrict__ P, int ldc,
    int Kslice) {
  __shared__ __bf16 sA[2][128 * 64];
  __shared__ __bf16 sB[2][64 * 64];

  const int tid = threadIdx.x;
  const int lane = tid & 63;
  const int w = tid >> 6;
  const int wm = w & 1, wn = w >> 1;
  const int row0 = blockIdx.y * 128;
  const int col0 = blockIdx.x * 64;
  const int koff = blockIdx.z * Kslice;

  const __bf16* gA[4]; int lofA[4];
  const __bf16* gB[2]; int lofB[2];
#pragma unroll
  for (int i = 0; i < 4; i++) {
    int c = i * 256 + tid;
    int m = c >> 3, cc = c & 7;
    int o = cc ^ (m & 7);
    gA[i] = A + (size_t)(row0 + m) * lda + koff + o * 8;
    lofA[i] = c * 8;
  }
#pragma unroll
  for (int i = 0; i < 2; i++) {
    int c = i * 256 + tid;
    int m = c >> 3, cc = c & 7;
    int o = cc ^ (m & 7);
    gB[i] = Bt + (size_t)(col0 + m) * ldb + koff + o * 8;
    lofB[i] = c * 8;
  }

  const int q = lane >> 4, r = lane & 15;
  int aoff[4][2], boff[2][2];
#pragma unroll
  for (int i = 0; i < 4; i++) {
    int ma = wm * 64 + i * 16 + r;
#pragma unroll
    for (int h = 0; h < 2; h++)
      aoff[i][h] = (ma * 8 + ((h * 4 + q) ^ (ma & 7))) * 8;
  }
#pragma unroll
  for (int j = 0; j < 2; j++) {
    int mb = wn * 32 + j * 16 + r;
#pragma unroll
    for (int h = 0; h < 2; h++)
      boff[j][h] = (mb * 8 + ((h * 4 + q) ^ (mb & 7))) * 8;
  }

  f32x4 acc[4][2] = {};

#pragma unroll
  for (int i = 0; i < 4; i++) gload_lds16(gA[i], &sA[0][0] + lofA[i]);
#pragma unroll
  for (int i = 0; i < 2; i++) gload_lds16(gB[i], &sB[0][0] + lofB[i]);

  int cur = 0;
  for (int k0 = 0; k0 < Kslice; k0 += 64) {
    __syncthreads();
    if (k0 + 64 < Kslice) {
      int nxt = cur ^ 1;
#pragma unroll
      for (int i = 0; i < 4; i++)
        gload_lds16(gA[i] + k0 + 64, &sA[nxt][0] + lofA[i]);
#pragma unroll
      for (int i = 0; i < 2; i++)
        gload_lds16(gB[i] + k0 + 64, &sB[nxt][0] + lofB[i]);
    }
#pragma unroll
    for (int h = 0; h < 2; h++) {
      bf16x8 af[4], bfr[2];
#pragma unroll
      for (int i = 0; i < 4; i++)
        af[i] = *(const bf16x8*)(&sA[cur][0] + aoff[i][h]);
#pragma unroll
      for (int j = 0; j < 2; j++)
        bfr[j] = *(const bf16x8*)(&sB[cur][0] + boff[j][h]);
#pragma unroll
      for (int i = 0; i < 4; i++)
#pragma unroll
        for (int j = 0; j < 2; j++)
          acc[i][j] = __builtin_amdgcn_mfma_f32_16x16x32_bf16(af[i], bfr[j],
                                                              acc[i][j], 0, 0, 0);
    }
    cur ^= 1;
  }

  float* Pz = P + (size_t)blockIdx.z * (size_t)gridDim.y * 128 * ldc;
#pragma unroll
  for (int i = 0; i < 4; i++) {
    int rowb = row0 + wm * 64 + i * 16 + q * 4;
#pragma unroll
    for (int j = 0; j < 2; j++) {
      int col = col0 + wn * 32 + j * 16 + r;
#pragma unroll
      for (int g = 0; g < 4; g++)
        Pz[(size_t)(rowb + g) * ldc + col] = acc[i][j][g];
    }
  }
}

// ---------------------------------------------------------------------------
// grad = sum of 4 split-K partials (scaled 1/512 for fp8 scales);
// z[:, off:off+512] += coef*dt*grad ; refresh zb (bf16) and zf8 (fp8).
// ---------------------------------------------------------------------------
__global__ void update_kernel(float* __restrict__ z, __bf16* __restrict__ zb,
                              unsigned char* __restrict__ zf8,
                              const float* __restrict__ gp,
                              const float* __restrict__ dt,
                              float coef, int off) {
  int t = blockIdx.x * blockDim.x + threadIdx.x;  // 0 .. NB*SD/4
  int b = t >> 7;
  int j4 = t & 127;
  const f32x4* g4 = (const f32x4*)gp;
  constexpr int STRIDE = NB * SD / 4;
  f32x4 g = g4[t] + g4[t + STRIDE] + g4[t + 2 * STRIDE] + g4[t + 3 * STRIDE];
  int zi4 = (b * ZD + off) / 4 + j4;
  f32x4 v = ((f32x4*)z)[zi4];
  float s = coef * dt[0] * (1.f / 512.f);  // undo x16(w) * x32(g1)
  v[0] += s * g[0]; v[1] += s * g[1]; v[2] += s * g[2]; v[3] += s * g[3];
  ((f32x4*)z)[zi4] = v;
  bf16x4 o;
  o[0] = (__bf16)v[0]; o[1] = (__bf16)v[1];
  o[2] = (__bf16)v[2]; o[3] = (__bf16)v[3];
  ((bf16x4*)zb)[zi4] = o;
  ((int*)zf8)[zi4] = pack_fp8x4(v[0], v[1], v[2], v[3]);
}

// ---------------------------------------------------------------------------
// W_out split-K=2 reduce + bias (f32, x4 vec)
// ---------------------------------------------------------------------------
__global__ void wout_reduce(const float* __restrict__ gp,
                            const float* __restrict__ b_out,
                            float* __restrict__ out) {
  int t = blockIdx.x * blockDim.x + threadIdx.x;  // 0 .. NB*1024/4
  constexpr int S = NB * 1024 / 4;
  const f32x4* g4 = (const f32x4*)gp;
  f32x4 v = g4[t] + g4[t + S];
  f32x4 bb = ((const f32x4*)b_out)[t & 255];
  v[0] += bb[0]; v[1] += bb[1]; v[2] += bb[2]; v[3] += bb[3];
  ((f32x4*)out)[t] = v;
}

// ---------------------------------------------------------------------------
// h_next: first 8 slices = z[:, :1024] (exact f32), rest zero
// ---------------------------------------------------------------------------
__global__ void hnext_kernel(const float* __restrict__ z,
                             float* __restrict__ out) {
  int t = blockIdx.x * blockDim.x + threadIdx.x;
  int i4 = t & 511;
  f32x4 zero = {0.f, 0.f, 0.f, 0.f};
  ((f32x4*)out)[t] = (i4 < 256) ? ((const f32x4*)z)[t] : zero;
}

// ---------------------------------------------------------------------------
extern "C" void kernel_launch(void* const* d_in, const int* in_sizes, int n_in,
                              void* d_out, int out_size, void* d_ws,
                              size_t ws_size, hipStream_t stream) {
  const float* x        = (const float*)d_in[0];
  const float* h_padded = (const float*)d_in[1];
  const float* W1    = (const float*)d_in[3];
  const float* b1    = (const float*)d_in[4];
  const float* W2    = (const float*)d_in[5];
  const float* b2    = (const float*)d_in[6];
  const float* W3    = (const float*)d_in[7];
  const float* W_out = (const float*)d_in[9];
  const float* b_out = (const float*)d_in[10];
  const float* enc_W = (const float*)d_in[11];
  const float* enc_b = (const float*)d_in[12];
  const float* thetas = (const float*)d_in[13];
  const float* gain   = (const float*)d_in[14];
  const float* shift  = (const float*)d_in[15];
  const float* cap_p  = (const float*)d_in[16];
  const float* t_bias = (const float*)d_in[17];
  const float* l_stab = (const float*)d_in[18];

  float* out_mat  = (float*)d_out;              // (2048,1024)
  float* out_hnxt = (float*)d_out + NB * 1024;  // (2048,16,128)

  // workspace layout (bytes)
  char* base = (char*)d_ws;
  float* z      = (float*)(base);                      // 16MB f32
  float* part   = (float*)(base + 16 * MB_);           // 16MB f32 partials
  __bf16* zb    = (__bf16*)(base + 32 * MB_);          // 8MB bf16
  __bf16* Wot   = (__bf16*)(base + 40 * MB_);          // 2MB bf16
  float* angl   = (float*)(base + 42 * MB_);           // 48KB
  float* accp   = (float*)(base + 42 * MB_ + 65536);   // scalars
  float* dtp    = accp + 1;
  unsigned char* zf8  = (unsigned char*)(base + 43 * MB_);  // 4MB each:
  unsigned char* h1_8 = zf8 + (size_t)NELEM_Z;
  unsigned char* g2_8 = h1_8 + (size_t)NELEM_Z;
  unsigned char* g1_8 = g2_8 + (size_t)NELEM_Z;
  unsigned char* W1n8 = g1_8 + (size_t)NELEM_Z;
  unsigned char* W1t8 = W1n8 + (size_t)NELEM_Z;
  unsigned char* W2n8 = W1t8 + (size_t)NELEM_Z;
  unsigned char* W2t8 = W2n8 + (size_t)NELEM_Z;

  dim3 thr256(256);
  dim3 thrT(32, 8);

  // 1. weight prep: fp8 (straight + transposed, x16) and bf16 W_out^T
  prep_w8<<<dim3(64, 64), thrT, 0, stream>>>(W1, W1n8, W1t8, ZD, ZD);
  prep_w8<<<dim3(64, 64), thrT, 0, stream>>>(W2, W2n8, W2t8, ZD, ZD);
  prep_w<<<dim3(32, 32), thrT, 0, stream>>>(W_out, Wot, 1024, 1024);

  // 2. build z (f32/bf16/fp8) + angles, fused; then sim + dt
  build_z_kernel<<<dim3(NB), thr256, 0, stream>>>(x, h_padded, enc_W, enc_b, z,
                                                  zb, zf8, angl, accp);
  sim_kernel<<<dim3(NB / 64), dim3(64), 0, stream>>>(angl, thetas, gain, shift,
                                                     accp);
  dt_kernel<<<dim3(1), dim3(1), 0, stream>>>(accp, cap_p, t_bias, l_stab, dtp);

  // 3. three leapfrog gradient evaluations (all-fp8 grad path)
  const int   j0r[3]  = {0, 512, 0};
  const int   offs[3] = {512, 0, 512};
  const float coef[3] = {-0.5f, 1.0f, -0.5f};

  dim3 gridSq(32, 16, 1);   // 2048x2048, 128x64 tiles -> 512 blocks (2/CU)
  dim3 gridGr(8, 16, 4);    // 2048x512, split-K=4     -> 512 blocks

  for (int i = 0; i < 3; i++) {
    // h1 = tanh(z @ W1 + b1)                       (fp8 out)
    mfma_gemm8<1><<<gridSq, thr256, 0, stream>>>(
        zf8, ZD, W1t8, ZD, h1_8, ZD, b1, nullptr, nullptr, 0, ZD);
    // g2 = 32*(1 - tanh(h1 @ W2 + b2)^2) * W3[col] (fp8 out)
    mfma_gemm8<2><<<gridSq, thr256, 0, stream>>>(
        h1_8, ZD, W2t8, ZD, g2_8, ZD, b2, W3, nullptr, 0, ZD);
    // g1 = (g2 @ W2^T)/16 * (1 - h1^2)             (fp8 out, carries x32)
    mfma_gemm8<3><<<gridSq, thr256, 0, stream>>>(
        g2_8, ZD, W2n8, ZD, g1_8, ZD, nullptr, nullptr, h1_8, ZD, ZD);
    // part = g1 @ W1[j0:j0+512,:]^T  (f32 partials, split-K=4)
    mfma_gemm8<0><<<gridGr, thr256, 0, stream>>>(
        g1_8, ZD, W1n8 + (size_t)j0r[i] * ZD, ZD, part, SD, nullptr, nullptr,
        nullptr, 0, 512);
    // z[:, offs] += coef*dt*sum(part)/512
    update_kernel<<<dim3(NB * SD / 4 / 256), thr256, 0, stream>>>(
        z, zb, zf8, part, dtp, coef[i], offs[i]);
  }

  // 4. out = z[:, :1024] @ W_out + b_out  (bf16, split-K=2 + reduce)
  mfma_gemm_bf16<<<dim3(16, 16, 2), thr256, 0, stream>>>(zb, ZD, Wot, 1024,
                                                         part, 1024, 512);
  wout_reduce<<<dim3(NB * 1024 / 4 / 256), thr256, 0, stream>>>(part, b_out,
                                                                out_mat);

  // 5. h_next writeback
  hnext_kernel<<<dim3(NELEM_Z / 4 / 256), thr256, 0, stream>>>(z, out_hnxt);
}